// Round 12
// baseline (691.978 us; speedup 1.0000x reference)
//
#include <hip/hip_runtime.h>
#include <math.h>

#define BLK 256
static const long LX = 4194304;   // input length per batch

typedef __bf16 bf16x8 __attribute__((ext_vector_type(8)));
typedef float  f32x4  __attribute__((ext_vector_type(4)));
typedef unsigned short u16;

// bijective XCD remap (m204): XCD k (= orig%8) executes a CONTIGUOUS chunk of the
// logical grid -> neighboring tiles (which share overlapping A rows) hit the same L2.
__device__ __forceinline__ int xcd_swz(int orig, int nwg) {
    int q = nwg >> 3, r = nwg & 7;
    int xcd = orig & 7, ii = orig >> 3;
    return (xcd < r ? xcd * (q + 1) : r * (q + 1) + (xcd - r) * q) + ii;
}

// split x = hi + lo, both bf16 (round-to-nearest-even)
__device__ __forceinline__ void bf16split(float x, u16& h, u16& l) {
    unsigned u = __float_as_uint(x);
    unsigned hr = (u + 0x7fffu + ((u >> 16) & 1u)) >> 16;
    h = (u16)hr;
    float hf = __uint_as_float(hr << 16);
    float r = x - hf;
    unsigned v = __float_as_uint(r);
    unsigned lr2 = (v + 0x7fffu + ((v >> 16) & 1u)) >> 16;
    l = (u16)lr2;
}

__device__ __forceinline__ float cin_val(const float* __restrict__ x, long xbase, int h, int w) {
    if ((unsigned)h >= 65536u || (unsigned)w >= 129u) return 0.f;
    long flat = (long)h * 129 + w;
    int n = (int)(flat >> 16);
    int q = (int)(flat & 65535);
    long pos = (long)n * 32768 + q;
    return (pos < LX) ? x[xbase + pos] : 0.f;
}

// ---------------- f0 conv1: MFMA implicit-GEMM over virtual c_in ----------------
__global__ __launch_bounds__(256)
void conv1_mfma_k(const float* __restrict__ x, const u16* __restrict__ wbh,
                  const u16* __restrict__ wbl, const float* __restrict__ bias,
                  u16* __restrict__ outh, u16* __restrict__ outl) {
    const long SPT = 240306;   // 10923*22 spatial per batch
    __shared__ u16 ph[6400];
    __shared__ u16 pl[6400];
    const int tid = threadIdx.x;
    const int b = blockIdx.y;
    const int bx = xcd_swz(blockIdx.x, gridDim.x);
    const long sp0 = (long)bx * 128;
    const long xbase = (long)b * LX;
    const int ho_min = (int)sp0 / 22;
    const int flat_start = (ho_min * 6 - 6) * 129 - 6;
    for (int i = tid; i < 6400; i += 256) {
        int flat = flat_start + i;
        float v = 0.f;
        if (flat >= 0 && flat < 65536 * 129) {
            int n = flat >> 16, q = flat & 65535;
            long pos = (long)n * 32768 + q;
            if (pos < LX) v = x[xbase + pos];
        }
        u16 h, l; bf16split(v, h, l);
        ph[i] = h; pl[i] = l;
    }
    __syncthreads();

    const int lane = tid & 63, wid = tid >> 6;
    const int lr = lane & 15;
    const int lk = (lane >> 4) << 3;

    int off0[2]; int wlo[2], whi[2];
#pragma unroll
    for (int fm = 0; fm < 2; fm++) {
        int r = (wid << 5) + (fm << 4) + lr;
        long spl = sp0 + r; if (spl >= SPT) spl = SPT - 1;
        int sp = (int)spl;
        int ho = sp / 22;
        int wo = sp - ho * 22;
        off0[fm] = (ho * 6 - 6) * 129 + (wo * 6 - 6) - flat_start;
        wlo[fm] = (wo == 0) ? 1 : 0;
        whi[fm] = (wo == 21) ? 1 : 0;
    }

    f32x4 acc[2][4];
#pragma unroll
    for (int fn = 0; fn < 4; fn++) {
        float bv = bias[(fn << 4) + lr];
#pragma unroll
        for (int fm = 0; fm < 2; fm++) { f32x4 v = {bv, bv, bv, bv}; acc[fm][fn] = v; }
    }

    const bool zhi = (lk >= 16);
#pragma unroll
    for (int c = 0; c < 5; c++) {
        bf16x8 bH[4], bL[4];
#pragma unroll
        for (int fn = 0; fn < 4; fn++) {
            int oc = (fn << 4) + lr;
            bH[fn] = *(const bf16x8*)(wbh + oc * 160 + (c << 5) + lk);
            bL[fn] = *(const bf16x8*)(wbl + oc * 160 + (c << 5) + lk);
        }
        bf16x8 aH[2], aL[2];
#pragma unroll
        for (int fm = 0; fm < 2; fm++) {
            union { bf16x8 v; u16 u[8]; } uh, ul;
            if (c == 4 && zhi) {
#pragma unroll
                for (int jj = 0; jj < 8; jj++) { uh.u[jj] = 0; ul.u[jj] = 0; }
            } else {
                int t0 = (c << 5) + lk;
                int kh0 = t0 / 12;
                int r0 = t0 - kh0 * 12;
                int jst = 12 - r0;
                int base = off0[fm] + t0 + kh0 * 117;
#pragma unroll
                for (int jj = 0; jj < 8; jj++) {
                    int wrapped = (jj >= jst) ? 1 : 0;
                    int idx = base + jj + (wrapped ? 117 : 0);
                    int kw = r0 + jj - (wrapped ? 12 : 0);
                    int bad = (wlo[fm] & ((kw < 6) ? 1 : 0)) | (whi[fm] & ((kw > 8) ? 1 : 0));
                    u16 hv = ph[idx];
                    u16 lv = pl[idx];
                    uh.u[jj] = bad ? (u16)0 : hv;
                    ul.u[jj] = bad ? (u16)0 : lv;
                }
            }
            aH[fm] = uh.v; aL[fm] = ul.v;
        }
#pragma unroll
        for (int fm = 0; fm < 2; fm++)
#pragma unroll
            for (int fn = 0; fn < 4; fn++) {
                acc[fm][fn] = __builtin_amdgcn_mfma_f32_16x16x32_bf16(aL[fm], bH[fn], acc[fm][fn], 0, 0, 0);
                acc[fm][fn] = __builtin_amdgcn_mfma_f32_16x16x32_bf16(aH[fm], bL[fn], acc[fm][fn], 0, 0, 0);
                acc[fm][fn] = __builtin_amdgcn_mfma_f32_16x16x32_bf16(aH[fm], bH[fn], acc[fm][fn], 0, 0, 0);
            }
    }
    const int row0 = (lane >> 4) << 2;
#pragma unroll
    for (int fm = 0; fm < 2; fm++) {
#pragma unroll
        for (int q = 0; q < 4; q++) {
            long sp = sp0 + (wid << 5) + (fm << 4) + row0 + q;
            if (sp < SPT) {
                long obase = ((long)b * SPT + sp) << 6;
#pragma unroll
                for (int fn = 0; fn < 4; fn++) {
                    u16 h, l;
                    bf16split(fmaxf(acc[fm][fn][q], 0.f), h, l);
                    outh[obase + (fn << 4) + lr] = h;
                    outl[obase + (fn << 4) + lr] = l;
                }
            }
        }
    }
}

// ---------------- f1 conv1: MFMA implicit-GEMM over the pooled plane ----------------
__global__ __launch_bounds__(256)
void conv1p_mfma_k(const float* __restrict__ pool, const u16* __restrict__ wbh,
                   const u16* __restrict__ wbl, const float* __restrict__ bias,
                   u16* __restrict__ outh, u16* __restrict__ outl) {
    const int SPT = 60082;       // 5462*11 spatial per batch
    const int HWP = 32769 * 65;  // pool plane size
    __shared__ u16 ph[5504];
    __shared__ u16 pl[5504];
    const int tid = threadIdx.x;
    const int b = blockIdx.y;
    const int bx = xcd_swz(blockIdx.x, gridDim.x);
    const long sp0 = (long)bx * 128;
    const float* pb = pool + (long)b * HWP;
    const int ho_min = (int)sp0 / 11;
    const int fs = (ho_min * 6 - 6) * 65 - 6;
    for (int i = tid; i < 5504; i += 256) {
        int flat = fs + i;
        float v = (flat >= 0 && flat < HWP) ? pb[flat] : 0.f;
        u16 h, l; bf16split(v, h, l);
        ph[i] = h; pl[i] = l;
    }
    __syncthreads();

    const int lane = tid & 63, wid = tid >> 6;
    const int lr = lane & 15;
    const int lk = (lane >> 4) << 3;

    int off0[2]; int wlo[2], whi[2];
#pragma unroll
    for (int fm = 0; fm < 2; fm++) {
        int r = (wid << 5) + (fm << 4) + lr;
        long spl = sp0 + r; if (spl >= SPT) spl = SPT - 1;
        int sp = (int)spl;
        int ho = sp / 11;
        int wo = sp - ho * 11;
        off0[fm] = (ho - ho_min) * 390 + wo * 6;
        wlo[fm] = (wo == 0) ? 1 : 0;
        whi[fm] = (wo == 10) ? 1 : 0;
    }

    f32x4 acc[2][4];
#pragma unroll
    for (int fn = 0; fn < 4; fn++) {
        float bv = bias[(fn << 4) + lr];
#pragma unroll
        for (int fm = 0; fm < 2; fm++) { f32x4 v = {bv, bv, bv, bv}; acc[fm][fn] = v; }
    }

    const bool zhi = (lk >= 16);
#pragma unroll
    for (int c = 0; c < 5; c++) {
        bf16x8 bH[4], bL[4];
#pragma unroll
        for (int fn = 0; fn < 4; fn++) {
            int oc = (fn << 4) + lr;
            bH[fn] = *(const bf16x8*)(wbh + oc * 160 + (c << 5) + lk);
            bL[fn] = *(const bf16x8*)(wbl + oc * 160 + (c << 5) + lk);
        }
        bf16x8 aH[2], aL[2];
#pragma unroll
        for (int fm = 0; fm < 2; fm++) {
            union { bf16x8 v; u16 u[8]; } uh, ul;
            if (c == 4 && zhi) {
#pragma unroll
                for (int jj = 0; jj < 8; jj++) { uh.u[jj] = 0; ul.u[jj] = 0; }
            } else {
                int t0 = (c << 5) + lk;
                int kh0 = t0 / 12;
                int r0 = t0 - kh0 * 12;
                int jst = 12 - r0;
                int base = off0[fm] + kh0 * 65 + r0;
#pragma unroll
                for (int jj = 0; jj < 8; jj++) {
                    int wrapped = (jj >= jst) ? 1 : 0;
                    int idx = base + jj + (wrapped ? 53 : 0);
                    int kw = r0 + jj - (wrapped ? 12 : 0);
                    int bad = (wlo[fm] & ((kw < 6) ? 1 : 0)) | (whi[fm] & ((kw > 10) ? 1 : 0));
                    u16 hv = ph[idx];
                    u16 lv = pl[idx];
                    uh.u[jj] = bad ? (u16)0 : hv;
                    ul.u[jj] = bad ? (u16)0 : lv;
                }
            }
            aH[fm] = uh.v; aL[fm] = ul.v;
        }
#pragma unroll
        for (int fm = 0; fm < 2; fm++)
#pragma unroll
            for (int fn = 0; fn < 4; fn++) {
                acc[fm][fn] = __builtin_amdgcn_mfma_f32_16x16x32_bf16(aL[fm], bH[fn], acc[fm][fn], 0, 0, 0);
                acc[fm][fn] = __builtin_amdgcn_mfma_f32_16x16x32_bf16(aH[fm], bL[fn], acc[fm][fn], 0, 0, 0);
                acc[fm][fn] = __builtin_amdgcn_mfma_f32_16x16x32_bf16(aH[fm], bH[fn], acc[fm][fn], 0, 0, 0);
            }
    }
    const int row0 = (lane >> 4) << 2;
#pragma unroll
    for (int fm = 0; fm < 2; fm++) {
#pragma unroll
        for (int q = 0; q < 4; q++) {
            long sp = sp0 + (wid << 5) + (fm << 4) + row0 + q;
            if (sp < SPT) {
                long obase = ((long)b * SPT + sp) << 6;
#pragma unroll
                for (int fn = 0; fn < 4; fn++) {
                    u16 h, l;
                    bf16split(fmaxf(acc[fm][fn][q], 0.f), h, l);
                    outh[obase + (fn << 4) + lr] = h;
                    outl[obase + (fn << 4) + lr] = l;
                }
            }
        }
    }
}

// ---------------- avgpool(2,2,pad=1,count_include_pad) straight from x ----------------
__global__ __launch_bounds__(BLK)
void avgpool_synth_k(const float* __restrict__ x, float* __restrict__ out, int B) {
    const int Ho = 32769, Wo = 65;
    long total = (long)B * Ho * Wo;
    long idx = (long)blockIdx.x * BLK + threadIdx.x;
    if (idx >= total) return;
    int w2 = (int)(idx % Wo);
    long t = idx / Wo;
    int p2 = (int)(t % Ho);
    int b  = (int)(t / Ho);
    long xbase = (long)b * LX;
    float s = 0.f;
#pragma unroll
    for (int dh = 0; dh < 2; dh++)
#pragma unroll
        for (int dw = 0; dw < 2; dw++)
            s += cin_val(x, xbase, 2 * p2 - 1 + dh, 2 * w2 - 1 + dw);
    out[idx] = 0.25f * s;
}

// ---------------- merged weight reorder: 9 jobs in one launch ----------------
struct RJob { const float* src; u16* dh; u16* dl; int Cout, Cin, Kk, type; long nel; };
struct RAll { RJob jobs[9]; int bstart[10]; };

__global__ __launch_bounds__(BLK)
void reorder_all_k(RAll a) {
    int bid = blockIdx.x;
    int ji = 0;
    while (ji < 8 && bid >= a.bstart[ji + 1]) ji++;
    RJob j = a.jobs[ji];
    long t = (long)(bid - a.bstart[ji]) * BLK + threadIdx.x;
    if (t >= j.nel) return;
    if (j.type == 0) {
        int tap = (int)(t % 160), oc = (int)(t / 160);
        float v = (tap < 144) ? j.src[oc * 144 + tap] : 0.f;
        u16 h, l; bf16split(v, h, l);
        j.dh[t] = h; j.dl[t] = l;
    } else {
        int kw = (int)(t % j.Kk);
        long r = t / j.Kk;
        int kh = (int)(r % j.Kk); r /= j.Kk;
        int ic = (int)(r % j.Cin);
        int oc = (int)(r / j.Cin);
        long dst = (long)oc * (j.Cin * j.Kk * j.Kk) + (long)(kh * j.Kk + kw) * j.Cin + ic;
        u16 h, l; bf16split(j.src[t], h, l);
        j.dh[dst] = h; j.dl[dst] = l;
    }
}

// ---------------- MFMA dual-job implicit-GEMM conv, bf16 hi/lo 3-term split-K ----------------
// R6/R8 structure (A+B in LDS, double-buffered, 64 KB, XOR swizzle -> 0 conflicts)
// + XCD blockIdx swizzle + DEPTH-2 register prefetch: each chunk's global loads are
// issued TWO chunks before their ds_write (two named register sets, loop unrolled x2),
// so the in-flight window (~2 chunks) covers HBM latency and the pre-store vmcnt
// never stalls. Same buffers/barriers per chunk -> correctness discipline unchanged.
struct MJob {
    const u16* Ah; const u16* Al; const u16* Wh; const u16* Wl;
    const float* bias; float* out; float* part;
    int Hin, Win, Cin, cshift, Cout, K, S, P, Hout, Wout, relu, nks;
    long total; int nbx; int Ktot;
};

__global__ __launch_bounds__(256)
void mgemm2_k(MJob j0, MJob j1, int split) {
    __shared__ u16 lds[2][4][128 * 32];   // [buf][Ah,Al,Bh,Bl][row*32 + swizzled col], 64 KB
    MJob j = j0;
    int bid = xcd_swz(blockIdx.x, gridDim.x);
    if (bid >= split) { j = j1; bid -= split; }
    const int bx = bid % j.nbx;
    int r2 = bid / j.nbx;
    const int nocb = j.Cout >> 7;
    const int ocb = (r2 % nocb) << 7;
    const int ks  = r2 / nocb;
    const int tid = threadIdx.x;
    const long spbase = (long)bx * 128;
    const int nchunk = j.Ktot >> 5;
    const int cbeg = (ks * nchunk) / j.nks;
    const int cend = ((ks + 1) * nchunk) / j.nks;

    const int sr = tid >> 1;
    const int sh = (tid & 1) << 4;
    long ssp = spbase + sr;
    const bool sval = ssp < j.total;
    long tt = sval ? ssp : 0;
    const int swo = (int)(tt % j.Wout); tt /= j.Wout;
    const int sho = (int)(tt % j.Hout);
    const int sb  = (int)(tt / j.Hout);
    const int sh0 = sho * j.S - j.P, sw0 = swo * j.S - j.P;
    const long ibase = (long)sb * j.Hin * j.Win;
    const long wbase = (long)(ocb + sr) * j.Ktot + sh;
    const int ssw = (sr >> 1) & 3;
    const int so0 = sr * 32 + ((((sh >> 3)    ) ^ ssw) << 3);
    const int so1 = sr * 32 + ((((sh >> 3) | 1) ^ ssw) << 3);

    // two named register sets (depth-2 pipeline; static indexing per rule #20)
    uint4 pA0, pA1, pL0, pL1, pB0, pB1, pM0, pM1;   // set P
    uint4 qA0, qA1, qL0, qL1, qB0, qB1, qM0, qM1;   // set Q
    auto addrA = [&](int c, long& ea, bool& ok) {
        int p0 = c << 5;
        int khw = p0 >> j.cshift;
        int ic0 = p0 - (khw << j.cshift);
        int kh = khw / j.K, kw = khw - kh * j.K;
        int h = sh0 + kh, w = sw0 + kw;
        ok = sval && (unsigned)h < (unsigned)j.Hin && (unsigned)w < (unsigned)j.Win;
        ea = (ibase + (long)h * j.Win + w) * j.Cin + ic0 + sh;
    };
    auto fetchP = [&](int c) {
        long ea; bool ok; addrA(c, ea, ok);
        uint4 z = make_uint4(0u, 0u, 0u, 0u);
        pA0 = ok ? *(const uint4*)(j.Ah + ea)     : z;
        pA1 = ok ? *(const uint4*)(j.Ah + ea + 8) : z;
        pL0 = ok ? *(const uint4*)(j.Al + ea)     : z;
        pL1 = ok ? *(const uint4*)(j.Al + ea + 8) : z;
        const long we = wbase + ((long)c << 5);
        pB0 = *(const uint4*)(j.Wh + we);
        pB1 = *(const uint4*)(j.Wh + we + 8);
        pM0 = *(const uint4*)(j.Wl + we);
        pM1 = *(const uint4*)(j.Wl + we + 8);
    };
    auto fetchQ = [&](int c) {
        long ea; bool ok; addrA(c, ea, ok);
        uint4 z = make_uint4(0u, 0u, 0u, 0u);
        qA0 = ok ? *(const uint4*)(j.Ah + ea)     : z;
        qA1 = ok ? *(const uint4*)(j.Ah + ea + 8) : z;
        qL0 = ok ? *(const uint4*)(j.Al + ea)     : z;
        qL1 = ok ? *(const uint4*)(j.Al + ea + 8) : z;
        const long we = wbase + ((long)c << 5);
        qB0 = *(const uint4*)(j.Wh + we);
        qB1 = *(const uint4*)(j.Wh + we + 8);
        qM0 = *(const uint4*)(j.Wl + we);
        qM1 = *(const uint4*)(j.Wl + we + 8);
    };
    auto storeP = [&](int buf) {
        *(uint4*)&lds[buf][0][so0] = pA0; *(uint4*)&lds[buf][0][so1] = pA1;
        *(uint4*)&lds[buf][1][so0] = pL0; *(uint4*)&lds[buf][1][so1] = pL1;
        *(uint4*)&lds[buf][2][so0] = pB0; *(uint4*)&lds[buf][2][so1] = pB1;
        *(uint4*)&lds[buf][3][so0] = pM0; *(uint4*)&lds[buf][3][so1] = pM1;
    };
    auto storeQ = [&](int buf) {
        *(uint4*)&lds[buf][0][so0] = qA0; *(uint4*)&lds[buf][0][so1] = qA1;
        *(uint4*)&lds[buf][1][so0] = qL0; *(uint4*)&lds[buf][1][so1] = qL1;
        *(uint4*)&lds[buf][2][so0] = qB0; *(uint4*)&lds[buf][2][so1] = qB1;
        *(uint4*)&lds[buf][3][so0] = qM0; *(uint4*)&lds[buf][3][so1] = qM1;
    };

    const int lane = tid & 63;
    const int wid = tid >> 6;
    const int wm = (wid >> 1) << 6, wn = (wid & 1) << 6;
    const int lr = lane & 15;
    const int lko = (((lane >> 4)) ^ ((lr >> 1) & 3)) << 3;

    f32x4 acc[4][4];
    if (j.nks == 1) {
#pragma unroll
        for (int fn = 0; fn < 4; fn++) {
            float b = j.bias[ocb + wn + fn * 16 + lr];
#pragma unroll
            for (int fm = 0; fm < 4; fm++) { f32x4 v = {b, b, b, b}; acc[fm][fn] = v; }
        }
    } else {
#pragma unroll
        for (int fm = 0; fm < 4; fm++)
#pragma unroll
            for (int fn = 0; fn < 4; fn++) { f32x4 v = {0.f, 0.f, 0.f, 0.f}; acc[fm][fn] = v; }
    }

    auto compute = [&](int cur) {
        const u16* Ahs = &lds[cur][0][0];
        const u16* Als = &lds[cur][1][0];
        const u16* Bhs = &lds[cur][2][0];
        const u16* Bls = &lds[cur][3][0];
        bf16x8 aH[4], aL[4], bH[4], bL[4];
#pragma unroll
        for (int f = 0; f < 4; f++) {
            aH[f] = *(const bf16x8*)(Ahs + (wm + f * 16 + lr) * 32 + lko);
            aL[f] = *(const bf16x8*)(Als + (wm + f * 16 + lr) * 32 + lko);
            bH[f] = *(const bf16x8*)(Bhs + (wn + f * 16 + lr) * 32 + lko);
            bL[f] = *(const bf16x8*)(Bls + (wn + f * 16 + lr) * 32 + lko);
        }
#pragma unroll
        for (int fm = 0; fm < 4; fm++)
#pragma unroll
            for (int fn = 0; fn < 4; fn++) {
                acc[fm][fn] = __builtin_amdgcn_mfma_f32_16x16x32_bf16(aL[fm], bH[fn], acc[fm][fn], 0, 0, 0);
                acc[fm][fn] = __builtin_amdgcn_mfma_f32_16x16x32_bf16(aH[fm], bL[fn], acc[fm][fn], 0, 0, 0);
                acc[fm][fn] = __builtin_amdgcn_mfma_f32_16x16x32_bf16(aH[fm], bH[fn], acc[fm][fn], 0, 0, 0);
            }
    };

    // prologue: chunk cbeg staged via P; chunk cbeg+1 in-flight in Q
    fetchP(cbeg); storeP(0);
    if (cbeg + 1 < cend) fetchQ(cbeg + 1);
    __syncthreads();

    for (int c = cbeg; c < cend; c += 2) {
        // even sub-iter: compute chunk c from buf0; Q holds data(c+1)
        if (c + 2 < cend) fetchP(c + 2);      // issued 2 chunks before its store
        compute(0);
        if (c + 1 < cend) storeQ(1);          // data(c+1): fetched >= 1 full chunk ago
        __syncthreads();
        if (c + 1 < cend) {
            // odd sub-iter: compute chunk c+1 from buf1; P holds data(c+2)
            if (c + 3 < cend) fetchQ(c + 3);
            compute(1);
            if (c + 2 < cend) storeP(0);      // data(c+2): fetched one chunk ago
            __syncthreads();
        }
    }

    const int row0 = (lane >> 4) << 2;
    if (j.nks == 1) {
#pragma unroll
        for (int fm = 0; fm < 4; fm++) {
#pragma unroll
            for (int q = 0; q < 4; q++) {
                long sp = spbase + wm + fm * 16 + row0 + q;
                if (sp < j.total) {
                    float* op = j.out + sp * j.Cout + ocb + wn + lr;
#pragma unroll
                    for (int fn = 0; fn < 4; fn++) {
                        float v = acc[fm][fn][q];
                        if (j.relu) v = fmaxf(v, 0.f);
                        op[fn * 16] = v;
                    }
                }
            }
        }
    } else {
        float* pb = j.part + ((long)ks * j.total) * j.Cout;
#pragma unroll
        for (int fm = 0; fm < 4; fm++) {
#pragma unroll
            for (int q = 0; q < 4; q++) {
                long sp = spbase + wm + fm * 16 + row0 + q;
                if (sp < j.total) {
                    float* op = pb + sp * j.Cout + ocb + wn + lr;
#pragma unroll
                    for (int fn = 0; fn < 4; fn++) op[fn * 16] = acc[fm][fn][q];
                }
            }
        }
    }
}

// ---------------- split-K combine: relu(bias + sum parts) -> bf16 hi/lo (and optional fp32) ----------------
struct CJob {
    const float* part; const float* bias;
    float* outf; u16* outh; u16* outl;
    long n; int C; int nks; int relu;
};

__global__ __launch_bounds__(BLK)
void combine2m_k(CJob a, CJob b) {
    long q0 = a.n * (long)a.C / 4, q1 = b.n * (long)b.C / 4;
    long id = (long)blockIdx.x * BLK + threadIdx.x;
    CJob j; long f4;
    if (id < q0) { j = a; f4 = id * 4; }
    else if (id < q0 + q1) { j = b; f4 = (id - q0) * 4; }
    else return;
    long stride = j.n * (long)j.C;
    int cb = (int)(f4 % j.C);
    float4 s = *(const float4*)(j.bias + cb);
    for (int ss = 0; ss < j.nks; ss++) {
        float4 p = *(const float4*)(j.part + ss * stride + f4);
        s.x += p.x; s.y += p.y; s.z += p.z; s.w += p.w;
    }
    if (j.relu) {
        s.x = fmaxf(s.x, 0.f); s.y = fmaxf(s.y, 0.f);
        s.z = fmaxf(s.z, 0.f); s.w = fmaxf(s.w, 0.f);
    }
    if (j.outf) *(float4*)(j.outf + f4) = s;
    if (j.outh) {
        u16 hx, hy, hz, hw2, la, lb, lc, ld;
        bf16split(s.x, hx, la); bf16split(s.y, hy, lb);
        bf16split(s.z, hz, lc); bf16split(s.w, hw2, ld);
        *(ushort4*)(j.outh + f4) = make_ushort4(hx, hy, hz, hw2);
        *(ushort4*)(j.outl + f4) = make_ushort4(la, lb, lc, ld);
    }
}

// ---------------- fused q+k 1x1 conv Cin=128 -> 16 on NHWC (fp32) ----------------
__global__ __launch_bounds__(256)
void qk2_k(const float* __restrict__ in,
           const float* __restrict__ qw, const float* __restrict__ qb,
           const float* __restrict__ kw2, const float* __restrict__ kb2,
           float* __restrict__ outq, float* __restrict__ outk, long total) {
    const float* w    = blockIdx.y ? kw2 : qw;
    const float* bias = blockIdx.y ? kb2 : qb;
    float* out        = blockIdx.y ? outk : outq;
    __shared__ float As[64 * 132];
    __shared__ float Ws[128 * 16];
    int tid = threadIdx.x;
    long spbase = (long)blockIdx.x * 64;
    int r = tid >> 2;
    int cpart = (tid & 3) << 5;
    long sp = spbase + r;
    bool ok = sp < total;
    const float* ip = in + sp * 128 + cpart;
#pragma unroll
    for (int jj = 0; jj < 8; jj++) {
        float4 v = ok ? *(const float4*)(ip + jj * 4) : make_float4(0.f, 0.f, 0.f, 0.f);
        *(float4*)&As[r * 132 + cpart + jj * 4] = v;
    }
    for (int t = tid; t < 2048; t += 256) Ws[(t & 127) * 16 + (t >> 7)] = w[t];
    __syncthreads();
    int ocp = (tid & 3) << 2;
    float acc[4] = {bias[ocp], bias[ocp + 1], bias[ocp + 2], bias[ocp + 3]};
    for (int ic = 0; ic < 128; ic++) {
        float a = As[r * 132 + ic];
#pragma unroll
        for (int jj = 0; jj < 4; jj++) acc[jj] = fmaf(a, Ws[ic * 16 + ocp + jj], acc[jj]);
    }
    if (ok) {
#pragma unroll
        for (int jj = 0; jj < 4; jj++) out[sp * 16 + ocp + jj] = acc[jj];
    }
}

// ---------------- flash criss-cross attention, split-KV partial pass (re-keyed PV) ----------------
struct AJob {
    const float* q; const float* kk; const float* v;
    float* pacc; float* pm; float* pl;
    int B, H, W, nrt, ns, ntile;
};

__global__ __launch_bounds__(256)
void cca_part_k(AJob j0, AJob j1, int n0) {
    const int RT = 16, TG = 64;
    __shared__ float lbuf[8192];     // 32 KB: [kls 64x17 | sc 16x68 | scales 16]; reused as reduce buf
    __shared__ float mlb2[32];
    float* kls    = lbuf;            // [64][17]
    float* sc     = lbuf + 1088;     // [16][68]
    float* scales = lbuf + 2176;     // [16]
    AJob j = j0;
    int bid = blockIdx.x;
    if (bid >= n0) { j = j1; bid -= n0; }
    int rt = bid % j.nrt; int t = bid / j.nrt;
    int ksp = t % j.ns; t /= j.ns;
    int w = t % j.W; int b = t / j.W;
    const int H = j.H, W = j.W;
    const int tid = threadIdx.x;
    const int r = tid >> 4, l16 = tid & 15;
    const int h = rt * RT + r;
    const int hc = (h < H) ? h : (H - 1);
    const long colbase = (long)b * H * W + w;
    const long rowbase = ((long)b * H + hc) * W;

    float qreg[16];
    {
        const float* qp = j.q + (rowbase + w) * 16;
#pragma unroll
        for (int jj = 0; jj < 4; jj++) {
            float4 t4 = *(const float4*)(qp + 4 * jj);
            qreg[4*jj] = t4.x; qreg[4*jj+1] = t4.y; qreg[4*jj+2] = t4.z; qreg[4*jj+3] = t4.w;
        }
    }
    const int lane6 = tid & 63;
    const int wid = tid >> 6;
    const int c2 = lane6 << 1;
    float accv[16][2];
#pragma unroll
    for (int i = 0; i < 16; i++) { accv[i][0] = 0.f; accv[i][1] = 0.f; }

    float m = -INFINITY, l = 0.f;
    const int gp = l16 * 4;

    const int tbeg = (ksp * j.ntile) / j.ns;
    const int tend = ((ksp + 1) * j.ntile) / j.ns;
    for (int tt2 = tbeg; tt2 < tend; tt2++) {
        const int g0 = tt2 * TG;
        {
            int kr = tid >> 2, kc = (tid & 3) << 2;
            int gg = g0 + kr;
            float4 kv = make_float4(0.f, 0.f, 0.f, 0.f);
            if (gg < H) kv = *(const float4*)(j.kk + (colbase + (long)gg * W) * 16 + kc);
            kls[kr * 17 + kc + 0] = kv.x; kls[kr * 17 + kc + 1] = kv.y;
            kls[kr * 17 + kc + 2] = kv.z; kls[kr * 17 + kc + 3] = kv.w;
        }
        __syncthreads();
        float sloc[4];
#pragma unroll
        for (int i = 0; i < 4; i++) {
            int gg = g0 + gp + i;
            float d = 0.f;
#pragma unroll
            for (int c = 0; c < 16; c++) d = fmaf(qreg[c], kls[(gp + i) * 17 + c], d);
            sloc[i] = (gg >= H || gg == h) ? -INFINITY : d;
        }
        float tmax = fmaxf(fmaxf(sloc[0], sloc[1]), fmaxf(sloc[2], sloc[3]));
#pragma unroll
        for (int off = 1; off < 16; off <<= 1) tmax = fmaxf(tmax, __shfl_xor(tmax, off, 16));
        float mt = fmaxf(m, tmax);
        float scale = __expf(m - mt);
        float ps = 0.f;
#pragma unroll
        for (int i = 0; i < 4; i++) {
            float p = __expf(sloc[i] - mt);
            ps += p;
            sc[r * 68 + gp + i] = p;
        }
#pragma unroll
        for (int off = 1; off < 16; off <<= 1) ps += __shfl_xor(ps, off, 16);
        l = l * scale + ps;
        m = mt;
        if (l16 == 0) scales[r] = scale;
        __syncthreads();
        {
            float4 sA = *(const float4*)&scales[0];
            float4 sB = *(const float4*)&scales[4];
            float4 sC = *(const float4*)&scales[8];
            float4 sD = *(const float4*)&scales[12];
            float sarr[16] = {sA.x,sA.y,sA.z,sA.w, sB.x,sB.y,sB.z,sB.w,
                              sC.x,sC.y,sC.z,sC.w, sD.x,sD.y,sD.z,sD.w};
#pragma unroll
            for (int row = 0; row < 16; row++) {
                accv[row][0] *= sarr[row];
                accv[row][1] *= sarr[row];
            }
#pragma unroll
            for (int s = 0; s < 2; s++) {
                const int k0 = (wid << 4) + (s << 3);
                float2 v2[8];
#pragma unroll
                for (int kq = 0; kq < 8; kq++) {
                    int gg = g0 + k0 + kq;
                    if (gg >= H) gg = H - 1;
                    v2[kq] = *(const float2*)(j.v + (colbase + (long)gg * W) * 128 + c2);
                }
#pragma unroll
                for (int row = 0; row < 16; row++) {
                    float4 pA = *(const float4*)&sc[row * 68 + k0];
                    float4 pB = *(const float4*)&sc[row * 68 + k0 + 4];
                    accv[row][0] = fmaf(pA.x, v2[0].x, accv[row][0]);
                    accv[row][1] = fmaf(pA.x, v2[0].y, accv[row][1]);
                    accv[row][0] = fmaf(pA.y, v2[1].x, accv[row][0]);
                    accv[row][1] = fmaf(pA.y, v2[1].y, accv[row][1]);
                    accv[row][0] = fmaf(pA.z, v2[2].x, accv[row][0]);
                    accv[row][1] = fmaf(pA.z, v2[2].y, accv[row][1]);
                    accv[row][0] = fmaf(pA.w, v2[3].x, accv[row][0]);
                    accv[row][1] = fmaf(pA.w, v2[3].y, accv[row][1]);
                    accv[row][0] = fmaf(pB.x, v2[4].x, accv[row][0]);
                    accv[row][1] = fmaf(pB.x, v2[4].y, accv[row][1]);
                    accv[row][0] = fmaf(pB.y, v2[5].x, accv[row][0]);
                    accv[row][1] = fmaf(pB.y, v2[5].y, accv[row][1]);
                    accv[row][0] = fmaf(pB.z, v2[6].x, accv[row][0]);
                    accv[row][1] = fmaf(pB.z, v2[6].y, accv[row][1]);
                    accv[row][0] = fmaf(pB.w, v2[7].x, accv[row][0]);
                    accv[row][1] = fmaf(pB.w, v2[7].y, accv[row][1]);
                }
            }
        }
        __syncthreads();
    }
    if (ksp == 0) {
        float sw[3];
        float twmax = -INFINITY;
#pragma unroll
        for (int jj = 0; jj < 3; jj++) {
            sw[jj] = -INFINITY;
            if (jj < W) {
                const float* kp = j.kk + (rowbase + jj) * 16;
                float d = 0.f;
#pragma unroll
                for (int c = 0; c < 16; c++) d = fmaf(qreg[c], kp[c], d);
                sw[jj] = d;
                twmax = fmaxf(twmax, d);
            }
        }
        float mt = fmaxf(m, twmax);
        float scale = __expf(m - mt);
        l *= scale;
#pragma unroll
        for (int jj = 0; jj < 3; jj++) {
            if (jj < W) {
                float p = __expf(sw[jj] - mt);
                l += p;
                if (l16 == 0) sc[r * 68 + jj] = p;
            }
        }
        m = mt;
        if (l16 == 0) scales[r] = scale;
    }
    if (l16 == 0) { mlb2[2 * r] = m; mlb2[2 * r + 1] = l; }
    __syncthreads();
    if (ksp == 0) {
        float4 sA = *(const float4*)&scales[0];
        float4 sB = *(const float4*)&scales[4];
        float4 sC = *(const float4*)&scales[8];
        float4 sD = *(const float4*)&scales[12];
        float sarr[16] = {sA.x,sA.y,sA.z,sA.w, sB.x,sB.y,sB.z,sB.w,
                          sC.x,sC.y,sC.z,sC.w, sD.x,sD.y,sD.z,sD.w};
#pragma unroll
        for (int row = 0; row < 16; row++) {
            accv[row][0] *= sarr[row];
            accv[row][1] *= sarr[row];
            int hr = rt * RT + row;
            int hcr = (hr < H) ? hr : (H - 1);
            long rb = ((long)b * H + hcr) * W;
#pragma unroll
            for (int jj = 0; jj < 3; jj++) {
                if (jj < W) {
                    float p = sc[row * 68 + jj];
                    float2 vv = *(const float2*)(j.v + (rb + jj) * 128 + c2);
                    accv[row][0] = fmaf(p, vv.x, accv[row][0]);
                    accv[row][1] = fmaf(p, vv.y, accv[row][1]);
                }
            }
        }
    }
    __syncthreads();
#pragma unroll
    for (int row = 0; row < 16; row++) {
        *(float2*)&lbuf[(wid << 11) + (row << 7) + c2] = make_float2(accv[row][0], accv[row][1]);
    }
    __syncthreads();
    {
        int orow = tid >> 4, ocb = (tid & 15) << 3;
        int hr = rt * RT + orow;
        if (hr < H) {
            float4 r0 = make_float4(0.f, 0.f, 0.f, 0.f);
            float4 r1 = make_float4(0.f, 0.f, 0.f, 0.f);
#pragma unroll
            for (int wv = 0; wv < 4; wv++) {
                float4 a0 = *(const float4*)&lbuf[(wv << 11) + (orow << 7) + ocb];
                float4 a1 = *(const float4*)&lbuf[(wv << 11) + (orow << 7) + ocb + 4];
                r0.x += a0.x; r0.y += a0.y; r0.z += a0.z; r0.w += a0.w;
                r1.x += a1.x; r1.y += a1.y; r1.z += a1.z; r1.w += a1.w;
            }
            long qi = ((long)b * H + hr) * W + w;
            float* pp = j.pacc + (qi * j.ns + ksp) * 128 + ocb;
            *(float4*)pp       = r0;
            *(float4*)(pp + 4) = r1;
            if ((tid & 15) == 0) {
                j.pm[qi * j.ns + ksp] = mlb2[2 * orow];
                j.pl[qi * j.ns + ksp] = mlb2[2 * orow + 1];
            }
        }
    }
}

// ---------------- CCA split combine: online-softmax merge + gamma*o + x ----------------
struct CCJob {
    const float* x; const float* pacc; const float* pm; const float* pl;
    float* out; long rows; int ns;
};

__global__ __launch_bounds__(BLK)
void cca_comb_k(CCJob a, CCJob b, const float* __restrict__ gamma) {
    long q0 = a.rows * 32, q1 = b.rows * 32;
    long id = (long)blockIdx.x * BLK + threadIdx.x;
    CCJob j; long lid;
    if (id < q0) { j = a; lid = id; }
    else if (id < q0 + q1) { j = b; lid = id - q0; }
    else return;
    long qi = lid >> 5;
    int c4 = (int)(lid & 31) << 2;
    int ns = j.ns;
    float M = -INFINITY;
    for (int s = 0; s < ns; s++) M = fmaxf(M, j.pm[qi * ns + s]);
    float L = 0.f;
    float4 acc = make_float4(0.f, 0.f, 0.f, 0.f);
    for (int s = 0; s < ns; s++) {
        float wgt = __expf(j.pm[qi * ns + s] - M);
        L += j.pl[qi * ns + s] * wgt;
        float4 p = *(const float4*)(j.pacc + (qi * ns + s) * 128 + c4);
        acc.x = fmaf(wgt, p.x, acc.x); acc.y = fmaf(wgt, p.y, acc.y);
        acc.z = fmaf(wgt, p.z, acc.z); acc.w = fmaf(wgt, p.w, acc.w);
    }
    float g = gamma[0] / L;
    float4 xr = *(const float4*)(j.x + qi * 128 + c4);
    float4 o = make_float4(g * acc.x + xr.x, g * acc.y + xr.y,
                           g * acc.z + xr.z, g * acc.w + xr.w);
    *(float4*)(j.out + qi * 128 + c4) = o;
}

// ---------------- partial channel-means over NHWC ----------------
__global__ __launch_bounds__(BLK)
void mean_part_k(const float* __restrict__ a, float* __restrict__ part, int HW, int NS) {
    int bx = blockIdx.x;
    int b = bx / NS, sc_ = bx % NS;
    int tid = threadIdx.x;
    int c = tid & 127, half = tid >> 7;
    int per = (HW + NS - 1) / NS;
    int s0 = sc_ * per, s1 = s0 + per; if (s1 > HW) s1 = HW;
    float acc = 0.f;
    for (int s = s0 + half; s < s1; s += 2) acc += a[((long)b * HW + s) * 128 + c];
    __shared__ float red[BLK];
    red[tid] = acc; __syncthreads();
    if (half == 0) part[(long)bx * 128 + c] = red[c] + red[c + 128];
}

// ---------------- combine partials -> feat, then 256->2 linear ----------------
__global__ __launch_bounds__(BLK)
void final2_k(const float* __restrict__ part0, const float* __restrict__ part1, int NS,
              const float* __restrict__ w, const float* __restrict__ bias,
              float* __restrict__ out, float hw0, float hw1) {
    __shared__ float feat[512];
    int tid = threadIdx.x;
    for (int t = tid; t < 512; t += BLK) {
        int b = t >> 8, c = t & 255;
        float s = 0.f;
        if (c < 128) {
            for (int ns = 0; ns < NS; ns++) s += part0[((long)b * NS + ns) * 128 + c];
            s /= hw0;
        } else {
            int cc = c - 128;
            for (int ns = 0; ns < NS; ns++) s += part1[((long)b * NS + ns) * 128 + cc];
            s /= hw1;
        }
        feat[t] = s;
    }
    __syncthreads();
    if (tid < 4) {
        int b = tid >> 1, jj = tid & 1;
        float s = bias[jj];
        for (int c = 0; c < 256; c++) s += feat[b * 256 + c] * w[jj * 256 + c];
        out[b * 2 + jj] = s;
    }
}

static inline long cdiv(long a, long b) { return (a + b - 1) / b; }

extern "C" void kernel_launch(void* const* d_in, const int* in_sizes, int n_in,
                              void* d_out, int out_size, void* d_ws, size_t ws_size,
                              hipStream_t stream) {
    const float* x     = (const float*)d_in[0];
    const float* f0w1  = (const float*)d_in[1];
    const float* f0b1  = (const float*)d_in[2];
    const float* f0w2  = (const float*)d_in[3];
    const float* f0b2  = (const float*)d_in[4];
    const float* f0w3  = (const float*)d_in[5];
    const float* f0b3  = (const float*)d_in[6];
    const float* f0w4  = (const float*)d_in[7];
    const float* f0b4  = (const float*)d_in[8];
    const float* f1w1  = (const float*)d_in[9];
    const float* f1b1  = (const float*)d_in[10];
    const float* f1w2  = (const float*)d_in[11];
    const float* f1b2  = (const float*)d_in[12];
    const float* f1w3  = (const float*)d_in[13];
    const float* f1b3  = (const float*)d_in[14];
    const float* f1w4  = (const float*)d_in[15];
    const float* f1b4  = (const float*)d_in[16];
    const float* qw    = (const float*)d_in[17];
    const float* qb    = (const float*)d_in[18];
    const float* kw    = (const float*)d_in[19];
    const float* kb    = (const float*)d_in[20];
    const float* vw    = (const float*)d_in[21];
    const float* vb    = (const float*)d_in[22];
    const float* gamma = (const float*)d_in[23];
    const float* clsw  = (const float*)d_in[24];
    const float* clsb  = (const float*)d_in[25];
    float* ws = (float*)d_ws;
    float* outp = (float*)d_out;

    const int B = 2;
    size_t off = 0;
    auto alloc = [&](size_t nfl) { size_t o = off; off += (nfl + 63) & ~(size_t)63; return o; };
    size_t o_pool = alloc((size_t)B * 32769 * 65);
    size_t o_A0h  = alloc((size_t)B * 10923 * 22 * 32);
    size_t o_A0l  = alloc((size_t)B * 10923 * 22 * 32);
    size_t o_A1h  = alloc((size_t)B * 5462 * 11 * 32);
    size_t o_A1l  = alloc((size_t)B * 5462 * 11 * 32);
    size_t o_B0h  = alloc((size_t)B * 2731 * 6 * 64);
    size_t o_B0l  = alloc((size_t)B * 2731 * 6 * 64);
    size_t o_c0   = alloc((size_t)B * 1366 * 3 * 128);
    size_t o_c1   = alloc((size_t)B * 683 * 2 * 128);
    size_t o_w1mh = alloc((size_t)64 * 160 / 2);
    size_t o_w1ml = alloc((size_t)64 * 160 / 2);
    size_t o_w1nh = alloc((size_t)64 * 160 / 2);
    size_t o_w1nl = alloc((size_t)64 * 160 / 2);
    size_t o_w2h0 = alloc((size_t)128 * 4096 / 2);
    size_t o_w2l0 = alloc((size_t)128 * 4096 / 2);
    size_t o_w2h1 = alloc((size_t)128 * 4096 / 2);
    size_t o_w2l1 = alloc((size_t)128 * 4096 / 2);
    size_t o_w3h0 = alloc((size_t)256 * 3200 / 2);
    size_t o_w3l0 = alloc((size_t)256 * 3200 / 2);
    size_t o_w3h1 = alloc((size_t)256 * 3200 / 2);
    size_t o_w3l1 = alloc((size_t)256 * 3200 / 2);
    size_t o_w4h0 = alloc((size_t)128 * 2304 / 2);
    size_t o_w4l0 = alloc((size_t)128 * 2304 / 2);
    size_t o_w4h1 = alloc((size_t)128 * 2304 / 2);
    size_t o_w4l1 = alloc((size_t)128 * 2304 / 2);
    size_t o_wvh  = alloc((size_t)128 * 128 / 2);
    size_t o_wvl  = alloc((size_t)128 * 128 / 2);
    size_t o_part = alloc((size_t)2 * (32772 + 8196) * 128);
    size_t need_main = off;
    size_t o_B1h = o_pool;
    size_t o_B1l = o_pool + (size_t)B * 1366 * 3 * 64;
    size_t sub = o_A0h;
    auto salloc = [&](size_t nfl) { size_t o = sub; sub += (nfl + 63) & ~(size_t)63; return o; };
    size_t o_C0h = salloc((size_t)B * 1366 * 3 * 128);
    size_t o_C0l = salloc((size_t)B * 1366 * 3 * 128);
    size_t o_C1h = salloc((size_t)B * 683 * 2 * 128);
    size_t o_C1l = salloc((size_t)B * 683 * 2 * 128);
    size_t o_c0h = salloc((size_t)B * 1366 * 3 * 64);
    size_t o_c0l = salloc((size_t)B * 1366 * 3 * 64);
    size_t o_c1h = salloc((size_t)B * 683 * 2 * 64);
    size_t o_c1l = salloc((size_t)B * 683 * 2 * 64);
    size_t o_q0  = salloc((size_t)B * 1366 * 3 * 16);
    size_t o_k0  = salloc((size_t)B * 1366 * 3 * 16);
    size_t o_v0  = salloc((size_t)B * 1366 * 3 * 128);
    size_t o_a0  = salloc((size_t)B * 1366 * 3 * 128);
    size_t o_q1  = salloc((size_t)B * 683 * 2 * 16);
    size_t o_k1  = salloc((size_t)B * 683 * 2 * 16);
    size_t o_v1  = salloc((size_t)B * 683 * 2 * 128);
    size_t o_a1  = salloc((size_t)B * 683 * 2 * 128);
    size_t o_p0  = salloc((size_t)B * 8 * 128);
    size_t o_p1  = salloc((size_t)B * 8 * 128);
    if (ws_size < need_main * sizeof(float)) {
        hipMemsetAsync(d_out, 0, (size_t)out_size * sizeof(float), stream);
        return;
    }
    auto U16 = [&](size_t o) { return (u16*)(ws + o); };

    {   // pooled branch input
        long tot = (long)B * 32769 * 65;
        avgpool_synth_k<<<dim3(cdiv(tot, BLK)), BLK, 0, stream>>>(x, ws + o_pool, B);
    }
    {   // all 9 weight reorders in ONE launch
        RAll ra;
        auto mkR = [&](int i, const float* src, size_t dh, size_t dl,
                       int Cout, int Cin, int Kk, int type, long nel) {
            ra.jobs[i] = { src, U16(dh), U16(dl), Cout, Cin, Kk, type, nel };
        };
        mkR(0, f0w1, o_w1mh, o_w1ml, 64, 1, 12, 0, 64 * 160);
        mkR(1, f1w1, o_w1nh, o_w1nl, 64, 1, 12, 0, 64 * 160);
        mkR(2, f0w2, o_w2h0, o_w2l0, 128, 64, 8, 1, (long)128 * 64 * 64);
        mkR(3, f1w2, o_w2h1, o_w2l1, 128, 64, 8, 1, (long)128 * 64 * 64);
        mkR(4, f0w3, o_w3h0, o_w3l0, 256, 128, 5, 1, (long)256 * 128 * 25);
        mkR(5, f1w3, o_w3h1, o_w3l1, 256, 128, 5, 1, (long)256 * 128 * 25);
        mkR(6, f0w4, o_w4h0, o_w4l0, 128, 256, 3, 1, (long)128 * 256 * 9);
        mkR(7, f1w4, o_w4h1, o_w4l1, 128, 256, 3, 1, (long)128 * 256 * 9);
        mkR(8, vw,   o_wvh,  o_wvl,  128, 128, 1, 1, (long)128 * 128);
        int acc2 = 0;
        for (int i = 0; i < 9; i++) {
            ra.bstart[i] = acc2;
            acc2 += (int)cdiv(ra.jobs[i].nel, BLK);
        }
        ra.bstart[9] = acc2;
        reorder_all_k<<<dim3(acc2), BLK, 0, stream>>>(ra);
    }
    {   // f1 conv1: MFMA patch kernel over pool plane -> A1 hi/lo
        int nbx = (int)cdiv(60082L, 128);   // 470
        conv1p_mfma_k<<<dim3(nbx, B), 256, 0, stream>>>(
            ws + o_pool, U16(o_w1nh), U16(o_w1nl), f1b1, U16(o_A1h), U16(o_A1l));
    }
    {   // f0 conv1: MFMA implicit GEMM over virtual c_in -> A0 hi/lo
        int nbx = (int)cdiv(240306L, 128);   // 1878
        conv1_mfma_k<<<dim3(nbx, B), 256, 0, stream>>>(
            x, U16(o_w1mh), U16(o_w1ml), f0b1, U16(o_A0h), U16(o_A0l));
    }

    float* partp = ws + o_part;
    auto mkM = [&](size_t ah, size_t al, size_t wh, size_t wl, const float* bias, float* out,
                   int Hin, int Win, int Cin, int cshift, int Cout,
                   int K, int S, int P, int Hout, int Wout, int relu) {
        MJob g;
        g.Ah = U16(ah); g.Al = U16(al); g.Wh = U16(wh); g.Wl = U16(wl);
        g.bias = bias; g.out = out; g.part = nullptr;
        g.Hin = Hin; g.Win = Win; g.Cin = Cin; g.cshift = cshift; g.Cout = Cout;
        g.K = K; g.S = S; g.P = P; g.Hout = Hout; g.Wout = Wout; g.relu = relu; g.nks = 1;
        g.total = (long)B * Hout * Wout;
        g.nbx = (int)((g.total + 127) / 128);
        g.Ktot = K * K * Cin;
        return g;
    };
    auto launchM = [&](MJob a, MJob b, int nks) {
        a.nks = nks; b.nks = nks;
        a.part = partp;
        b.part = partp + (size_t)nks * a.total * a.Cout;
        int na = a.nbx * (a.Cout >> 7) * nks;
        int nb = b.nbx * (b.Cout >> 7) * nks;
        mgemm2_k<<<dim3(na + nb), 256, 0, stream>>>(a, b, na);
    };

    // conv2: A0/A1 -> B0/B1 (bf16 hi/lo), split-K 2
    {
        MJob a = mkM(o_A0h, o_A0l, o_w2h0, o_w2l0, f0b2, nullptr, 10923, 22, 64, 6, 128, 8, 4, 4, 2731, 6, 1);
        MJob b = mkM(o_A1h, o_A1l, o_w2h1, o_w2l1, f1b2, nullptr, 5462, 11, 64, 6, 128, 8, 4, 4, 1366, 3, 1);
        launchM(a, b, 2);
        CJob ca = {partp, f0b2, nullptr, U16(o_B0h), U16(o_B0l), a.total, 128, 2, 1};
        CJob cb = {partp + (size_t)2 * a.total * 128, f1b2, nullptr, U16(o_B1h), U16(o_B1l), b.total, 128, 2, 1};
        long n4 = (a.total * 128 + b.total * 128) / 4;
        combine2m_k<<<dim3(cdiv(n4, BLK)), BLK, 0, stream>>>(ca, cb);
    }
    // conv3: B0/B1 -> C0/C1 (bf16 hi/lo), split-K 3
    {
        MJob a = mkM(o_B0h, o_B0l, o_w3h0, o_w3l0, f0b3, nullptr, 2731, 6, 128, 7, 256, 5, 2, 2, 1366, 3, 1);
        MJob b = mkM(o_B1h, o_B1l, o_w3h1, o_w3l1, f1b3, nullptr, 1366, 3, 128, 7, 256, 5, 2, 2, 683, 2, 1);
        launchM(a, b, 3);
        CJob ca = {partp, f0b3, nullptr, U16(o_C0h), U16(o_C0l), a.total, 256, 3, 1};
        CJob cb = {partp + (size_t)3 * a.total * 256, f1b3, nullptr, U16(o_C1h), U16(o_C1l), b.total, 256, 3, 1};
        long n4 = (a.total * 256 + b.total * 256) / 4;
        combine2m_k<<<dim3(cdiv(n4, BLK)), BLK, 0, stream>>>(ca, cb);
    }
    // conv4: C0/C1 -> c0/c1 (fp32 + bf16 hi/lo), split-K 6
    {
        MJob a = mkM(o_C0h, o_C0l, o_w4h0, o_w4l0, f0b4, nullptr, 1366, 3, 256, 8, 128, 3, 1, 1, 1366, 3, 1);
        MJob b = mkM(o_C1h, o_C1l, o_w4h1, o_w4l1, f1b4, nullptr, 683, 2, 256, 8, 128, 3, 1, 1, 683, 2, 1);
        launchM(a, b, 6);
        CJob ca = {partp, f0b4, ws + o_c0, U16(o_c0h), U16(o_c0l), a.total, 128, 6, 1};
        CJob cb = {partp + (size_t)6 * a.total * 128, f1b4, ws + o_c1, U16(o_c1h), U16(o_c1l), b.total, 128, 6, 1};
        long n4 = (a.total * 128 + b.total * 128) / 4;
        combine2m_k<<<dim3(cdiv(n4, BLK)), BLK, 0, stream>>>(ca, cb);
    }
    // q,k projections (fp32 from c0/c1)
    {
        long tot0 = (long)B * 1366 * 3;
        qk2_k<<<dim3(cdiv(tot0, 64), 2), 256, 0, stream>>>(
            ws + o_c0, qw, qb, kw, kb, ws + o_q0, ws + o_k0, tot0);
        long tot1 = (long)B * 683 * 2;
        qk2_k<<<dim3(cdiv(tot1, 64), 2), 256, 0, stream>>>(
            ws + o_c1, qw, qb, kw, kb, ws + o_q1, ws + o_k1, tot1);
    }
    // v projection (MFMA, nks=1, direct fp32 out, no relu)
    {
        MJob a = mkM(o_c0h, o_c0l, o_wvh, o_wvl, vb, ws + o_v0, 1366, 3, 128, 7, 128, 1, 1, 0, 1366, 3, 0);
        MJob b = mkM(o_c1h, o_c1l, o_wvh, o_wvl, vb, ws + o_v1, 683, 2, 128, 7, 128, 1, 1, 0, 683, 2, 0);
        launchM(a, b, 1);
    }
    // CCA: split-KV flash partials (both branches, one launch) + combine
    {
        const int nrt0 = 86, nrt1 = 43;
        const int ns0 = 6, ns1 = 3;
        const long rows0 = (long)B * 1366 * 3;   // 8196
        const long rows1 = (long)B * 683 * 2;    // 2732
        size_t pp = o_part;
        auto palloc = [&](size_t nfl) { size_t o = pp; pp += (nfl + 63) & ~(size_t)63; return o; };
        size_t o_pa0 = palloc((size_t)rows0 * ns0 * 128);
        size_t o_pm0 = palloc((size_t)rows0 * ns0);
        size_t o_pl0 = palloc((size_t)rows0 * ns0);
        size_t o_pa1 = palloc((size_t)rows1 * ns1 * 128);
        size_t o_pm1 = palloc((size_t)rows1 * ns1);
        size_t o_pl1 = palloc((size_t)rows1 * ns1);
        AJob a0 = { ws + o_q0, ws + o_k0, ws + o_v0,
                    ws + o_pa0, ws + o_pm0, ws + o_pl0, B, 1366, 3, nrt0, ns0, 22 };
        AJob a1 = { ws + o_q1, ws + o_k1, ws + o_v1,
                    ws + o_pa1, ws + o_pm1, ws + o_pl1, B, 683, 2, nrt1, ns1, 11 };
        int n0 = B * 3 * nrt0 * ns0;   // 3096
        int n1 = B * 2 * nrt1 * ns1;   // 516
        cca_part_k<<<dim3(n0 + n1), 256, 0, stream>>>(a0, a1, n0);
        CCJob c0 = { ws + o_c0, ws + o_pa0, ws + o_pm0, ws + o_pl0, ws + o_a0, rows0, ns0 };
        CCJob c1 = { ws + o_c1, ws + o_pa1, ws + o_pm1, ws + o_pl1, ws + o_a1, rows1, ns1 };
        long tot = (rows0 + rows1) * 32;
        cca_comb_k<<<dim3(cdiv(tot, BLK)), BLK, 0, stream>>>(c0, c1, gamma);
    }
    // means + classifier
    mean_part_k<<<dim3(B * 8), BLK, 0, stream>>>(ws + o_a0, ws + o_p0, 1366 * 3, 8);
    mean_part_k<<<dim3(B * 8), BLK, 0, stream>>>(ws + o_a1, ws + o_p1, 683 * 2, 8);
    final2_k<<<dim3(1), BLK, 0, stream>>>(ws + o_p0, ws + o_p1, 8, clsw, clsb, outp,
                                          (float)(1366 * 3), (float)(683 * 2));
}

// Round 13
// 687.656 us; speedup vs baseline: 1.0063x; 1.0063x over previous
//
#include <hip/hip_runtime.h>
#include <math.h>

#define BLK 256
static const long LX = 4194304;   // input length per batch

typedef __bf16 bf16x8 __attribute__((ext_vector_type(8)));
typedef float  f32x4  __attribute__((ext_vector_type(4)));
typedef unsigned short u16;

// bijective XCD remap (m204): XCD k (= orig%8) executes a CONTIGUOUS chunk of the
// logical grid -> neighboring tiles (which share overlapping A rows) hit the same L2.
__device__ __forceinline__ int xcd_swz(int orig, int nwg) {
    int q = nwg >> 3, r = nwg & 7;
    int xcd = orig & 7, ii = orig >> 3;
    return (xcd < r ? xcd * (q + 1) : r * (q + 1) + (xcd - r) * q) + ii;
}

// split x = hi + lo, both bf16 (round-to-nearest-even)
__device__ __forceinline__ void bf16split(float x, u16& h, u16& l) {
    unsigned u = __float_as_uint(x);
    unsigned hr = (u + 0x7fffu + ((u >> 16) & 1u)) >> 16;
    h = (u16)hr;
    float hf = __uint_as_float(hr << 16);
    float r = x - hf;
    unsigned v = __float_as_uint(r);
    unsigned lr2 = (v + 0x7fffu + ((v >> 16) & 1u)) >> 16;
    l = (u16)lr2;
}

__device__ __forceinline__ float cin_val(const float* __restrict__ x, long xbase, int h, int w) {
    if ((unsigned)h >= 65536u || (unsigned)w >= 129u) return 0.f;
    long flat = (long)h * 129 + w;
    int n = (int)(flat >> 16);
    int q = (int)(flat & 65535);
    long pos = (long)n * 32768 + q;
    return (pos < LX) ? x[xbase + pos] : 0.f;
}

// ---------------- f0 conv1: MFMA implicit-GEMM over virtual c_in ----------------
__global__ __launch_bounds__(256)
void conv1_mfma_k(const float* __restrict__ x, const u16* __restrict__ wbh,
                  const u16* __restrict__ wbl, const float* __restrict__ bias,
                  u16* __restrict__ outh, u16* __restrict__ outl) {
    const long SPT = 240306;   // 10923*22 spatial per batch
    __shared__ u16 ph[6400];
    __shared__ u16 pl[6400];
    const int tid = threadIdx.x;
    const int b = blockIdx.y;
    const int bx = xcd_swz(blockIdx.x, gridDim.x);
    const long sp0 = (long)bx * 128;
    const long xbase = (long)b * LX;
    const int ho_min = (int)sp0 / 22;
    const int flat_start = (ho_min * 6 - 6) * 129 - 6;
    for (int i = tid; i < 6400; i += 256) {
        int flat = flat_start + i;
        float v = 0.f;
        if (flat >= 0 && flat < 65536 * 129) {
            int n = flat >> 16, q = flat & 65535;
            long pos = (long)n * 32768 + q;
            if (pos < LX) v = x[xbase + pos];
        }
        u16 h, l; bf16split(v, h, l);
        ph[i] = h; pl[i] = l;
    }
    __syncthreads();

    const int lane = tid & 63, wid = tid >> 6;
    const int lr = lane & 15;
    const int lk = (lane >> 4) << 3;

    int off0[2]; int wlo[2], whi[2];
#pragma unroll
    for (int fm = 0; fm < 2; fm++) {
        int r = (wid << 5) + (fm << 4) + lr;
        long spl = sp0 + r; if (spl >= SPT) spl = SPT - 1;
        int sp = (int)spl;
        int ho = sp / 22;
        int wo = sp - ho * 22;
        off0[fm] = (ho * 6 - 6) * 129 + (wo * 6 - 6) - flat_start;
        wlo[fm] = (wo == 0) ? 1 : 0;
        whi[fm] = (wo == 21) ? 1 : 0;
    }

    f32x4 acc[2][4];
#pragma unroll
    for (int fn = 0; fn < 4; fn++) {
        float bv = bias[(fn << 4) + lr];
#pragma unroll
        for (int fm = 0; fm < 2; fm++) { f32x4 v = {bv, bv, bv, bv}; acc[fm][fn] = v; }
    }

    const bool zhi = (lk >= 16);
#pragma unroll
    for (int c = 0; c < 5; c++) {
        bf16x8 bH[4], bL[4];
#pragma unroll
        for (int fn = 0; fn < 4; fn++) {
            int oc = (fn << 4) + lr;
            bH[fn] = *(const bf16x8*)(wbh + oc * 160 + (c << 5) + lk);
            bL[fn] = *(const bf16x8*)(wbl + oc * 160 + (c << 5) + lk);
        }
        bf16x8 aH[2], aL[2];
#pragma unroll
        for (int fm = 0; fm < 2; fm++) {
            union { bf16x8 v; u16 u[8]; } uh, ul;
            if (c == 4 && zhi) {
#pragma unroll
                for (int jj = 0; jj < 8; jj++) { uh.u[jj] = 0; ul.u[jj] = 0; }
            } else {
                int t0 = (c << 5) + lk;
                int kh0 = t0 / 12;
                int r0 = t0 - kh0 * 12;
                int jst = 12 - r0;
                int base = off0[fm] + t0 + kh0 * 117;
#pragma unroll
                for (int jj = 0; jj < 8; jj++) {
                    int wrapped = (jj >= jst) ? 1 : 0;
                    int idx = base + jj + (wrapped ? 117 : 0);
                    int kw = r0 + jj - (wrapped ? 12 : 0);
                    int bad = (wlo[fm] & ((kw < 6) ? 1 : 0)) | (whi[fm] & ((kw > 8) ? 1 : 0));
                    u16 hv = ph[idx];
                    u16 lv = pl[idx];
                    uh.u[jj] = bad ? (u16)0 : hv;
                    ul.u[jj] = bad ? (u16)0 : lv;
                }
            }
            aH[fm] = uh.v; aL[fm] = ul.v;
        }
#pragma unroll
        for (int fm = 0; fm < 2; fm++)
#pragma unroll
            for (int fn = 0; fn < 4; fn++) {
                acc[fm][fn] = __builtin_amdgcn_mfma_f32_16x16x32_bf16(aL[fm], bH[fn], acc[fm][fn], 0, 0, 0);
                acc[fm][fn] = __builtin_amdgcn_mfma_f32_16x16x32_bf16(aH[fm], bL[fn], acc[fm][fn], 0, 0, 0);
                acc[fm][fn] = __builtin_amdgcn_mfma_f32_16x16x32_bf16(aH[fm], bH[fn], acc[fm][fn], 0, 0, 0);
            }
    }
    const int row0 = (lane >> 4) << 2;
#pragma unroll
    for (int fm = 0; fm < 2; fm++) {
#pragma unroll
        for (int q = 0; q < 4; q++) {
            long sp = sp0 + (wid << 5) + (fm << 4) + row0 + q;
            if (sp < SPT) {
                long obase = ((long)b * SPT + sp) << 6;
#pragma unroll
                for (int fn = 0; fn < 4; fn++) {
                    u16 h, l;
                    bf16split(fmaxf(acc[fm][fn][q], 0.f), h, l);
                    outh[obase + (fn << 4) + lr] = h;
                    outl[obase + (fn << 4) + lr] = l;
                }
            }
        }
    }
}

// ---------------- f1 conv1: MFMA implicit-GEMM over the pooled plane ----------------
__global__ __launch_bounds__(256)
void conv1p_mfma_k(const float* __restrict__ pool, const u16* __restrict__ wbh,
                   const u16* __restrict__ wbl, const float* __restrict__ bias,
                   u16* __restrict__ outh, u16* __restrict__ outl) {
    const int SPT = 60082;       // 5462*11 spatial per batch
    const int HWP = 32769 * 65;  // pool plane size
    __shared__ u16 ph[5504];
    __shared__ u16 pl[5504];
    const int tid = threadIdx.x;
    const int b = blockIdx.y;
    const int bx = xcd_swz(blockIdx.x, gridDim.x);
    const long sp0 = (long)bx * 128;
    const float* pb = pool + (long)b * HWP;
    const int ho_min = (int)sp0 / 11;
    const int fs = (ho_min * 6 - 6) * 65 - 6;
    for (int i = tid; i < 5504; i += 256) {
        int flat = fs + i;
        float v = (flat >= 0 && flat < HWP) ? pb[flat] : 0.f;
        u16 h, l; bf16split(v, h, l);
        ph[i] = h; pl[i] = l;
    }
    __syncthreads();

    const int lane = tid & 63, wid = tid >> 6;
    const int lr = lane & 15;
    const int lk = (lane >> 4) << 3;

    int off0[2]; int wlo[2], whi[2];
#pragma unroll
    for (int fm = 0; fm < 2; fm++) {
        int r = (wid << 5) + (fm << 4) + lr;
        long spl = sp0 + r; if (spl >= SPT) spl = SPT - 1;
        int sp = (int)spl;
        int ho = sp / 11;
        int wo = sp - ho * 11;
        off0[fm] = (ho - ho_min) * 390 + wo * 6;
        wlo[fm] = (wo == 0) ? 1 : 0;
        whi[fm] = (wo == 10) ? 1 : 0;
    }

    f32x4 acc[2][4];
#pragma unroll
    for (int fn = 0; fn < 4; fn++) {
        float bv = bias[(fn << 4) + lr];
#pragma unroll
        for (int fm = 0; fm < 2; fm++) { f32x4 v = {bv, bv, bv, bv}; acc[fm][fn] = v; }
    }

    const bool zhi = (lk >= 16);
#pragma unroll
    for (int c = 0; c < 5; c++) {
        bf16x8 bH[4], bL[4];
#pragma unroll
        for (int fn = 0; fn < 4; fn++) {
            int oc = (fn << 4) + lr;
            bH[fn] = *(const bf16x8*)(wbh + oc * 160 + (c << 5) + lk);
            bL[fn] = *(const bf16x8*)(wbl + oc * 160 + (c << 5) + lk);
        }
        bf16x8 aH[2], aL[2];
#pragma unroll
        for (int fm = 0; fm < 2; fm++) {
            union { bf16x8 v; u16 u[8]; } uh, ul;
            if (c == 4 && zhi) {
#pragma unroll
                for (int jj = 0; jj < 8; jj++) { uh.u[jj] = 0; ul.u[jj] = 0; }
            } else {
                int t0 = (c << 5) + lk;
                int kh0 = t0 / 12;
                int r0 = t0 - kh0 * 12;
                int jst = 12 - r0;
                int base = off0[fm] + kh0 * 65 + r0;
#pragma unroll
                for (int jj = 0; jj < 8; jj++) {
                    int wrapped = (jj >= jst) ? 1 : 0;
                    int idx = base + jj + (wrapped ? 53 : 0);
                    int kw = r0 + jj - (wrapped ? 12 : 0);
                    int bad = (wlo[fm] & ((kw < 6) ? 1 : 0)) | (whi[fm] & ((kw > 10) ? 1 : 0));
                    u16 hv = ph[idx];
                    u16 lv = pl[idx];
                    uh.u[jj] = bad ? (u16)0 : hv;
                    ul.u[jj] = bad ? (u16)0 : lv;
                }
            }
            aH[fm] = uh.v; aL[fm] = ul.v;
        }
#pragma unroll
        for (int fm = 0; fm < 2; fm++)
#pragma unroll
            for (int fn = 0; fn < 4; fn++) {
                acc[fm][fn] = __builtin_amdgcn_mfma_f32_16x16x32_bf16(aL[fm], bH[fn], acc[fm][fn], 0, 0, 0);
                acc[fm][fn] = __builtin_amdgcn_mfma_f32_16x16x32_bf16(aH[fm], bL[fn], acc[fm][fn], 0, 0, 0);
                acc[fm][fn] = __builtin_amdgcn_mfma_f32_16x16x32_bf16(aH[fm], bH[fn], acc[fm][fn], 0, 0, 0);
            }
    }
    const int row0 = (lane >> 4) << 2;
#pragma unroll
    for (int fm = 0; fm < 2; fm++) {
#pragma unroll
        for (int q = 0; q < 4; q++) {
            long sp = sp0 + (wid << 5) + (fm << 4) + row0 + q;
            if (sp < SPT) {
                long obase = ((long)b * SPT + sp) << 6;
#pragma unroll
                for (int fn = 0; fn < 4; fn++) {
                    u16 h, l;
                    bf16split(fmaxf(acc[fm][fn][q], 0.f), h, l);
                    outh[obase + (fn << 4) + lr] = h;
                    outl[obase + (fn << 4) + lr] = l;
                }
            }
        }
    }
}

// ---------------- avgpool(2,2,pad=1,count_include_pad) straight from x ----------------
__global__ __launch_bounds__(BLK)
void avgpool_synth_k(const float* __restrict__ x, float* __restrict__ out, int B) {
    const int Ho = 32769, Wo = 65;
    long total = (long)B * Ho * Wo;
    long idx = (long)blockIdx.x * BLK + threadIdx.x;
    if (idx >= total) return;
    int w2 = (int)(idx % Wo);
    long t = idx / Wo;
    int p2 = (int)(t % Ho);
    int b  = (int)(t / Ho);
    long xbase = (long)b * LX;
    float s = 0.f;
#pragma unroll
    for (int dh = 0; dh < 2; dh++)
#pragma unroll
        for (int dw = 0; dw < 2; dw++)
            s += cin_val(x, xbase, 2 * p2 - 1 + dh, 2 * w2 - 1 + dw);
    out[idx] = 0.25f * s;
}

// ---------------- merged weight reorder: 9 jobs in one launch ----------------
struct RJob { const float* src; u16* dh; u16* dl; int Cout, Cin, Kk, type; long nel; };
struct RAll { RJob jobs[9]; int bstart[10]; };

__global__ __launch_bounds__(BLK)
void reorder_all_k(RAll a) {
    int bid = blockIdx.x;
    int ji = 0;
    while (ji < 8 && bid >= a.bstart[ji + 1]) ji++;
    RJob j = a.jobs[ji];
    long t = (long)(bid - a.bstart[ji]) * BLK + threadIdx.x;
    if (t >= j.nel) return;
    if (j.type == 0) {
        int tap = (int)(t % 160), oc = (int)(t / 160);
        float v = (tap < 144) ? j.src[oc * 144 + tap] : 0.f;
        u16 h, l; bf16split(v, h, l);
        j.dh[t] = h; j.dl[t] = l;
    } else {
        int kw = (int)(t % j.Kk);
        long r = t / j.Kk;
        int kh = (int)(r % j.Kk); r /= j.Kk;
        int ic = (int)(r % j.Cin);
        int oc = (int)(r / j.Cin);
        long dst = (long)oc * (j.Cin * j.Kk * j.Kk) + (long)(kh * j.Kk + kw) * j.Cin + ic;
        u16 h, l; bf16split(j.src[t], h, l);
        j.dh[dst] = h; j.dl[dst] = l;
    }
}

// ---------------- MFMA dual-job implicit-GEMM conv, bf16 hi/lo 3-term split-K ----------------
// R6/R8 structure: A+B staged in LDS (double-buffered, 64 KB) + XOR bank-swizzle
// (g ^= (row>>1)&3 on both store and read) -> zero bank conflicts.
// + bijective XCD blockIdx swizzle: neighboring spatial tiles share im2col overlap
// rows -> same-XCD L2 hits instead of independent HBM fetches.
struct MJob {
    const u16* Ah; const u16* Al; const u16* Wh; const u16* Wl;
    const float* bias; float* out; float* part;
    int Hin, Win, Cin, cshift, Cout, K, S, P, Hout, Wout, relu, nks;
    long total; int nbx; int Ktot;
};

__global__ __launch_bounds__(256)
void mgemm2_k(MJob j0, MJob j1, int split) {
    __shared__ u16 lds[2][4][128 * 32];   // [buf][Ah,Al,Bh,Bl][row*32 + swizzled col], 64 KB
    MJob j = j0;
    int bid = xcd_swz(blockIdx.x, gridDim.x);
    if (bid >= split) { j = j1; bid -= split; }
    const int bx = bid % j.nbx;
    int r2 = bid / j.nbx;
    const int nocb = j.Cout >> 7;
    const int ocb = (r2 % nocb) << 7;
    const int ks  = r2 / nocb;
    const int tid = threadIdx.x;
    const long spbase = (long)bx * 128;
    const int nchunk = j.Ktot >> 5;
    const int cbeg = (ks * nchunk) / j.nks;
    const int cend = ((ks + 1) * nchunk) / j.nks;

    const int sr = tid >> 1;
    const int sh = (tid & 1) << 4;
    long ssp = spbase + sr;
    const bool sval = ssp < j.total;
    long tt = sval ? ssp : 0;
    const int swo = (int)(tt % j.Wout); tt /= j.Wout;
    const int sho = (int)(tt % j.Hout);
    const int sb  = (int)(tt / j.Hout);
    const int sh0 = sho * j.S - j.P, sw0 = swo * j.S - j.P;
    const long ibase = (long)sb * j.Hin * j.Win;
    const long wbase = (long)(ocb + sr) * j.Ktot + sh;
    const int ssw = (sr >> 1) & 3;
    const int so0 = sr * 32 + ((((sh >> 3)    ) ^ ssw) << 3);
    const int so1 = sr * 32 + ((((sh >> 3) | 1) ^ ssw) << 3);

    uint4 rA0, rA1, rL0, rL1, rB0, rB1, rM0, rM1;
    auto fetch = [&](int c) {
        int p0 = c << 5;
        int khw = p0 >> j.cshift;
        int ic0 = p0 - (khw << j.cshift);
        int kh = khw / j.K, kw = khw - kh * j.K;
        int h = sh0 + kh, w = sw0 + kw;
        bool ok = sval && (unsigned)h < (unsigned)j.Hin && (unsigned)w < (unsigned)j.Win;
        uint4 z = make_uint4(0u, 0u, 0u, 0u);
        const long e = (ibase + (long)h * j.Win + w) * j.Cin + ic0 + sh;
        rA0 = ok ? *(const uint4*)(j.Ah + e)     : z;
        rA1 = ok ? *(const uint4*)(j.Ah + e + 8) : z;
        rL0 = ok ? *(const uint4*)(j.Al + e)     : z;
        rL1 = ok ? *(const uint4*)(j.Al + e + 8) : z;
        const long we = wbase + p0;
        rB0 = *(const uint4*)(j.Wh + we);
        rB1 = *(const uint4*)(j.Wh + we + 8);
        rM0 = *(const uint4*)(j.Wl + we);
        rM1 = *(const uint4*)(j.Wl + we + 8);
    };
    auto store = [&](int buf) {
        *(uint4*)&lds[buf][0][so0] = rA0; *(uint4*)&lds[buf][0][so1] = rA1;
        *(uint4*)&lds[buf][1][so0] = rL0; *(uint4*)&lds[buf][1][so1] = rL1;
        *(uint4*)&lds[buf][2][so0] = rB0; *(uint4*)&lds[buf][2][so1] = rB1;
        *(uint4*)&lds[buf][3][so0] = rM0; *(uint4*)&lds[buf][3][so1] = rM1;
    };

    const int lane = tid & 63;
    const int wid = tid >> 6;
    const int wm = (wid >> 1) << 6, wn = (wid & 1) << 6;
    const int lr = lane & 15;
    const int lko = (((lane >> 4)) ^ ((lr >> 1) & 3)) << 3;

    f32x4 acc[4][4];
    if (j.nks == 1) {
#pragma unroll
        for (int fn = 0; fn < 4; fn++) {
            float b = j.bias[ocb + wn + fn * 16 + lr];
#pragma unroll
            for (int fm = 0; fm < 4; fm++) { f32x4 v = {b, b, b, b}; acc[fm][fn] = v; }
        }
    } else {
#pragma unroll
        for (int fm = 0; fm < 4; fm++)
#pragma unroll
            for (int fn = 0; fn < 4; fn++) { f32x4 v = {0.f, 0.f, 0.f, 0.f}; acc[fm][fn] = v; }
    }

    fetch(cbeg); store(0);
    __syncthreads();

    for (int c = cbeg; c < cend; c++) {
        const int cur = (c - cbeg) & 1, nxt = cur ^ 1;
        const bool more = (c + 1 < cend);
        if (more) fetch(c + 1);
        const u16* Ahs = &lds[cur][0][0];
        const u16* Als = &lds[cur][1][0];
        const u16* Bhs = &lds[cur][2][0];
        const u16* Bls = &lds[cur][3][0];
        bf16x8 aH[4], aL[4], bH[4], bL[4];
#pragma unroll
        for (int f = 0; f < 4; f++) {
            aH[f] = *(const bf16x8*)(Ahs + (wm + f * 16 + lr) * 32 + lko);
            aL[f] = *(const bf16x8*)(Als + (wm + f * 16 + lr) * 32 + lko);
            bH[f] = *(const bf16x8*)(Bhs + (wn + f * 16 + lr) * 32 + lko);
            bL[f] = *(const bf16x8*)(Bls + (wn + f * 16 + lr) * 32 + lko);
        }
#pragma unroll
        for (int fm = 0; fm < 4; fm++)
#pragma unroll
            for (int fn = 0; fn < 4; fn++) {
                acc[fm][fn] = __builtin_amdgcn_mfma_f32_16x16x32_bf16(aL[fm], bH[fn], acc[fm][fn], 0, 0, 0);
                acc[fm][fn] = __builtin_amdgcn_mfma_f32_16x16x32_bf16(aH[fm], bL[fn], acc[fm][fn], 0, 0, 0);
                acc[fm][fn] = __builtin_amdgcn_mfma_f32_16x16x32_bf16(aH[fm], bH[fn], acc[fm][fn], 0, 0, 0);
            }
        if (more) store(nxt);
        __syncthreads();
    }

    const int row0 = (lane >> 4) << 2;
    if (j.nks == 1) {
#pragma unroll
        for (int fm = 0; fm < 4; fm++) {
#pragma unroll
            for (int q = 0; q < 4; q++) {
                long sp = spbase + wm + fm * 16 + row0 + q;
                if (sp < j.total) {
                    float* op = j.out + sp * j.Cout + ocb + wn + lr;
#pragma unroll
                    for (int fn = 0; fn < 4; fn++) {
                        float v = acc[fm][fn][q];
                        if (j.relu) v = fmaxf(v, 0.f);
                        op[fn * 16] = v;
                    }
                }
            }
        }
    } else {
        float* pb = j.part + ((long)ks * j.total) * j.Cout;
#pragma unroll
        for (int fm = 0; fm < 4; fm++) {
#pragma unroll
            for (int q = 0; q < 4; q++) {
                long sp = spbase + wm + fm * 16 + row0 + q;
                if (sp < j.total) {
                    float* op = pb + sp * j.Cout + ocb + wn + lr;
#pragma unroll
                    for (int fn = 0; fn < 4; fn++) op[fn * 16] = acc[fm][fn][q];
                }
            }
        }
    }
}

// ---------------- split-K combine: relu(bias + sum parts) -> bf16 hi/lo (and optional fp32) ----------------
struct CJob {
    const float* part; const float* bias;
    float* outf; u16* outh; u16* outl;
    long n; int C; int nks; int relu;
};

__global__ __launch_bounds__(BLK)
void combine2m_k(CJob a, CJob b) {
    long q0 = a.n * (long)a.C / 4, q1 = b.n * (long)b.C / 4;
    long id = (long)blockIdx.x * BLK + threadIdx.x;
    CJob j; long f4;
    if (id < q0) { j = a; f4 = id * 4; }
    else if (id < q0 + q1) { j = b; f4 = (id - q0) * 4; }
    else return;
    long stride = j.n * (long)j.C;
    int cb = (int)(f4 % j.C);
    float4 s = *(const float4*)(j.bias + cb);
    for (int ss = 0; ss < j.nks; ss++) {
        float4 p = *(const float4*)(j.part + ss * stride + f4);
        s.x += p.x; s.y += p.y; s.z += p.z; s.w += p.w;
    }
    if (j.relu) {
        s.x = fmaxf(s.x, 0.f); s.y = fmaxf(s.y, 0.f);
        s.z = fmaxf(s.z, 0.f); s.w = fmaxf(s.w, 0.f);
    }
    if (j.outf) *(float4*)(j.outf + f4) = s;
    if (j.outh) {
        u16 hx, hy, hz, hw2, la, lb, lc, ld;
        bf16split(s.x, hx, la); bf16split(s.y, hy, lb);
        bf16split(s.z, hz, lc); bf16split(s.w, hw2, ld);
        *(ushort4*)(j.outh + f4) = make_ushort4(hx, hy, hz, hw2);
        *(ushort4*)(j.outl + f4) = make_ushort4(la, lb, lc, ld);
    }
}

// ---------------- fused q+k 1x1 conv Cin=128 -> 16 on NHWC (fp32) ----------------
__global__ __launch_bounds__(256)
void qk2_k(const float* __restrict__ in,
           const float* __restrict__ qw, const float* __restrict__ qb,
           const float* __restrict__ kw2, const float* __restrict__ kb2,
           float* __restrict__ outq, float* __restrict__ outk, long total) {
    const float* w    = blockIdx.y ? kw2 : qw;
    const float* bias = blockIdx.y ? kb2 : qb;
    float* out        = blockIdx.y ? outk : outq;
    __shared__ float As[64 * 132];
    __shared__ float Ws[128 * 16];
    int tid = threadIdx.x;
    long spbase = (long)blockIdx.x * 64;
    int r = tid >> 2;
    int cpart = (tid & 3) << 5;
    long sp = spbase + r;
    bool ok = sp < total;
    const float* ip = in + sp * 128 + cpart;
#pragma unroll
    for (int jj = 0; jj < 8; jj++) {
        float4 v = ok ? *(const float4*)(ip + jj * 4) : make_float4(0.f, 0.f, 0.f, 0.f);
        *(float4*)&As[r * 132 + cpart + jj * 4] = v;
    }
    for (int t = tid; t < 2048; t += 256) Ws[(t & 127) * 16 + (t >> 7)] = w[t];
    __syncthreads();
    int ocp = (tid & 3) << 2;
    float acc[4] = {bias[ocp], bias[ocp + 1], bias[ocp + 2], bias[ocp + 3]};
    for (int ic = 0; ic < 128; ic++) {
        float a = As[r * 132 + ic];
#pragma unroll
        for (int jj = 0; jj < 4; jj++) acc[jj] = fmaf(a, Ws[ic * 16 + ocp + jj], acc[jj]);
    }
    if (ok) {
#pragma unroll
        for (int jj = 0; jj < 4; jj++) out[sp * 16 + ocp + jj] = acc[jj];
    }
}

// ---------------- flash criss-cross attention, split-KV partial pass (re-keyed PV) ----------------
struct AJob {
    const float* q; const float* kk; const float* v;
    float* pacc; float* pm; float* pl;
    int B, H, W, nrt, ns, ntile;
};

__global__ __launch_bounds__(256)
void cca_part_k(AJob j0, AJob j1, int n0) {
    const int RT = 16, TG = 64;
    __shared__ float lbuf[8192];     // 32 KB: [kls 64x17 | sc 16x68 | scales 16]; reused as reduce buf
    __shared__ float mlb2[32];
    float* kls    = lbuf;            // [64][17]
    float* sc     = lbuf + 1088;     // [16][68]
    float* scales = lbuf + 2176;     // [16]
    AJob j = j0;
    int bid = blockIdx.x;
    if (bid >= n0) { j = j1; bid -= n0; }
    int rt = bid % j.nrt; int t = bid / j.nrt;
    int ksp = t % j.ns; t /= j.ns;
    int w = t % j.W; int b = t / j.W;
    const int H = j.H, W = j.W;
    const int tid = threadIdx.x;
    const int r = tid >> 4, l16 = tid & 15;
    const int h = rt * RT + r;
    const int hc = (h < H) ? h : (H - 1);
    const long colbase = (long)b * H * W + w;
    const long rowbase = ((long)b * H + hc) * W;

    float qreg[16];
    {
        const float* qp = j.q + (rowbase + w) * 16;
#pragma unroll
        for (int jj = 0; jj < 4; jj++) {
            float4 t4 = *(const float4*)(qp + 4 * jj);
            qreg[4*jj] = t4.x; qreg[4*jj+1] = t4.y; qreg[4*jj+2] = t4.z; qreg[4*jj+3] = t4.w;
        }
    }
    const int lane6 = tid & 63;
    const int wid = tid >> 6;
    const int c2 = lane6 << 1;
    float accv[16][2];
#pragma unroll
    for (int i = 0; i < 16; i++) { accv[i][0] = 0.f; accv[i][1] = 0.f; }

    float m = -INFINITY, l = 0.f;
    const int gp = l16 * 4;

    const int tbeg = (ksp * j.ntile) / j.ns;
    const int tend = ((ksp + 1) * j.ntile) / j.ns;
    for (int tt2 = tbeg; tt2 < tend; tt2++) {
        const int g0 = tt2 * TG;
        {
            int kr = tid >> 2, kc = (tid & 3) << 2;
            int gg = g0 + kr;
            float4 kv = make_float4(0.f, 0.f, 0.f, 0.f);
            if (gg < H) kv = *(const float4*)(j.kk + (colbase + (long)gg * W) * 16 + kc);
            kls[kr * 17 + kc + 0] = kv.x; kls[kr * 17 + kc + 1] = kv.y;
            kls[kr * 17 + kc + 2] = kv.z; kls[kr * 17 + kc + 3] = kv.w;
        }
        __syncthreads();
        float sloc[4];
#pragma unroll
        for (int i = 0; i < 4; i++) {
            int gg = g0 + gp + i;
            float d = 0.f;
#pragma unroll
            for (int c = 0; c < 16; c++) d = fmaf(qreg[c], kls[(gp + i) * 17 + c], d);
            sloc[i] = (gg >= H || gg == h) ? -INFINITY : d;
        }
        float tmax = fmaxf(fmaxf(sloc[0], sloc[1]), fmaxf(sloc[2], sloc[3]));
#pragma unroll
        for (int off = 1; off < 16; off <<= 1) tmax = fmaxf(tmax, __shfl_xor(tmax, off, 16));
        float mt = fmaxf(m, tmax);
        float scale = __expf(m - mt);
        float ps = 0.f;
#pragma unroll
        for (int i = 0; i < 4; i++) {
            float p = __expf(sloc[i] - mt);
            ps += p;
            sc[r * 68 + gp + i] = p;
        }
#pragma unroll
        for (int off = 1; off < 16; off <<= 1) ps += __shfl_xor(ps, off, 16);
        l = l * scale + ps;
        m = mt;
        if (l16 == 0) scales[r] = scale;
        __syncthreads();
        {
            float4 sA = *(const float4*)&scales[0];
            float4 sB = *(const float4*)&scales[4];
            float4 sC = *(const float4*)&scales[8];
            float4 sD = *(const float4*)&scales[12];
            float sarr[16] = {sA.x,sA.y,sA.z,sA.w, sB.x,sB.y,sB.z,sB.w,
                              sC.x,sC.y,sC.z,sC.w, sD.x,sD.y,sD.z,sD.w};
#pragma unroll
            for (int row = 0; row < 16; row++) {
                accv[row][0] *= sarr[row];
                accv[row][1] *= sarr[row];
            }
#pragma unroll
            for (int s = 0; s < 2; s++) {
                const int k0 = (wid << 4) + (s << 3);
                float2 v2[8];
#pragma unroll
                for (int kq = 0; kq < 8; kq++) {
                    int gg = g0 + k0 + kq;
                    if (gg >= H) gg = H - 1;
                    v2[kq] = *(const float2*)(j.v + (colbase + (long)gg * W) * 128 + c2);
                }
#pragma unroll
                for (int row = 0; row < 16; row++) {
                    float4 pA = *(const float4*)&sc[row * 68 + k0];
                    float4 pB = *(const float4*)&sc[row * 68 + k0 + 4];
                    accv[row][0] = fmaf(pA.x, v2[0].x, accv[row][0]);
                    accv[row][1] = fmaf(pA.x, v2[0].y, accv[row][1]);
                    accv[row][0] = fmaf(pA.y, v2[1].x, accv[row][0]);
                    accv[row][1] = fmaf(pA.y, v2[1].y, accv[row][1]);
                    accv[row][0] = fmaf(pA.z, v2[2].x, accv[row][0]);
                    accv[row][1] = fmaf(pA.z, v2[2].y, accv[row][1]);
                    accv[row][0] = fmaf(pA.w, v2[3].x, accv[row][0]);
                    accv[row][1] = fmaf(pA.w, v2[3].y, accv[row][1]);
                    accv[row][0] = fmaf(pB.x, v2[4].x, accv[row][0]);
                    accv[row][1] = fmaf(pB.x, v2[4].y, accv[row][1]);
                    accv[row][0] = fmaf(pB.y, v2[5].x, accv[row][0]);
                    accv[row][1] = fmaf(pB.y, v2[5].y, accv[row][1]);
                    accv[row][0] = fmaf(pB.z, v2[6].x, accv[row][0]);
                    accv[row][1] = fmaf(pB.z, v2[6].y, accv[row][1]);
                    accv[row][0] = fmaf(pB.w, v2[7].x, accv[row][0]);
                    accv[row][1] = fmaf(pB.w, v2[7].y, accv[row][1]);
                }
            }
        }
        __syncthreads();
    }
    if (ksp == 0) {
        float sw[3];
        float twmax = -INFINITY;
#pragma unroll
        for (int jj = 0; jj < 3; jj++) {
            sw[jj] = -INFINITY;
            if (jj < W) {
                const float* kp = j.kk + (rowbase + jj) * 16;
                float d = 0.f;
#pragma unroll
                for (int c = 0; c < 16; c++) d = fmaf(qreg[c], kp[c], d);
                sw[jj] = d;
                twmax = fmaxf(twmax, d);
            }
        }
        float mt = fmaxf(m, twmax);
        float scale = __expf(m - mt);
        l *= scale;
#pragma unroll
        for (int jj = 0; jj < 3; jj++) {
            if (jj < W) {
                float p = __expf(sw[jj] - mt);
                l += p;
                if (l16 == 0) sc[r * 68 + jj] = p;
            }
        }
        m = mt;
        if (l16 == 0) scales[r] = scale;
    }
    if (l16 == 0) { mlb2[2 * r] = m; mlb2[2 * r + 1] = l; }
    __syncthreads();
    if (ksp == 0) {
        float4 sA = *(const float4*)&scales[0];
        float4 sB = *(const float4*)&scales[4];
        float4 sC = *(const float4*)&scales[8];
        float4 sD = *(const float4*)&scales[12];
        float sarr[16] = {sA.x,sA.y,sA.z,sA.w, sB.x,sB.y,sB.z,sB.w,
                          sC.x,sC.y,sC.z,sC.w, sD.x,sD.y,sD.z,sD.w};
#pragma unroll
        for (int row = 0; row < 16; row++) {
            accv[row][0] *= sarr[row];
            accv[row][1] *= sarr[row];
            int hr = rt * RT + row;
            int hcr = (hr < H) ? hr : (H - 1);
            long rb = ((long)b * H + hcr) * W;
#pragma unroll
            for (int jj = 0; jj < 3; jj++) {
                if (jj < W) {
                    float p = sc[row * 68 + jj];
                    float2 vv = *(const float2*)(j.v + (rb + jj) * 128 + c2);
                    accv[row][0] = fmaf(p, vv.x, accv[row][0]);
                    accv[row][1] = fmaf(p, vv.y, accv[row][1]);
                }
            }
        }
    }
    __syncthreads();
#pragma unroll
    for (int row = 0; row < 16; row++) {
        *(float2*)&lbuf[(wid << 11) + (row << 7) + c2] = make_float2(accv[row][0], accv[row][1]);
    }
    __syncthreads();
    {
        int orow = tid >> 4, ocb = (tid & 15) << 3;
        int hr = rt * RT + orow;
        if (hr < H) {
            float4 r0 = make_float4(0.f, 0.f, 0.f, 0.f);
            float4 r1 = make_float4(0.f, 0.f, 0.f, 0.f);
#pragma unroll
            for (int wv = 0; wv < 4; wv++) {
                float4 a0 = *(const float4*)&lbuf[(wv << 11) + (orow << 7) + ocb];
                float4 a1 = *(const float4*)&lbuf[(wv << 11) + (orow << 7) + ocb + 4];
                r0.x += a0.x; r0.y += a0.y; r0.z += a0.z; r0.w += a0.w;
                r1.x += a1.x; r1.y += a1.y; r1.z += a1.z; r1.w += a1.w;
            }
            long qi = ((long)b * H + hr) * W + w;
            float* pp = j.pacc + (qi * j.ns + ksp) * 128 + ocb;
            *(float4*)pp       = r0;
            *(float4*)(pp + 4) = r1;
            if ((tid & 15) == 0) {
                j.pm[qi * j.ns + ksp] = mlb2[2 * orow];
                j.pl[qi * j.ns + ksp] = mlb2[2 * orow + 1];
            }
        }
    }
}

// ---------------- CCA split combine: online-softmax merge + gamma*o + x ----------------
struct CCJob {
    const float* x; const float* pacc; const float* pm; const float* pl;
    float* out; long rows; int ns;
};

__global__ __launch_bounds__(BLK)
void cca_comb_k(CCJob a, CCJob b, const float* __restrict__ gamma) {
    long q0 = a.rows * 32, q1 = b.rows * 32;
    long id = (long)blockIdx.x * BLK + threadIdx.x;
    CCJob j; long lid;
    if (id < q0) { j = a; lid = id; }
    else if (id < q0 + q1) { j = b; lid = id - q0; }
    else return;
    long qi = lid >> 5;
    int c4 = (int)(lid & 31) << 2;
    int ns = j.ns;
    float M = -INFINITY;
    for (int s = 0; s < ns; s++) M = fmaxf(M, j.pm[qi * ns + s]);
    float L = 0.f;
    float4 acc = make_float4(0.f, 0.f, 0.f, 0.f);
    for (int s = 0; s < ns; s++) {
        float wgt = __expf(j.pm[qi * ns + s] - M);
        L += j.pl[qi * ns + s] * wgt;
        float4 p = *(const float4*)(j.pacc + (qi * ns + s) * 128 + c4);
        acc.x = fmaf(wgt, p.x, acc.x); acc.y = fmaf(wgt, p.y, acc.y);
        acc.z = fmaf(wgt, p.z, acc.z); acc.w = fmaf(wgt, p.w, acc.w);
    }
    float g = gamma[0] / L;
    float4 xr = *(const float4*)(j.x + qi * 128 + c4);
    float4 o = make_float4(g * acc.x + xr.x, g * acc.y + xr.y,
                           g * acc.z + xr.z, g * acc.w + xr.w);
    *(float4*)(j.out + qi * 128 + c4) = o;
}

// ---------------- partial channel-means over NHWC ----------------
__global__ __launch_bounds__(BLK)
void mean_part_k(const float* __restrict__ a, float* __restrict__ part, int HW, int NS) {
    int bx = blockIdx.x;
    int b = bx / NS, sc_ = bx % NS;
    int tid = threadIdx.x;
    int c = tid & 127, half = tid >> 7;
    int per = (HW + NS - 1) / NS;
    int s0 = sc_ * per, s1 = s0 + per; if (s1 > HW) s1 = HW;
    float acc = 0.f;
    for (int s = s0 + half; s < s1; s += 2) acc += a[((long)b * HW + s) * 128 + c];
    __shared__ float red[BLK];
    red[tid] = acc; __syncthreads();
    if (half == 0) part[(long)bx * 128 + c] = red[c] + red[c + 128];
}

// ---------------- combine partials -> feat, then 256->2 linear ----------------
__global__ __launch_bounds__(BLK)
void final2_k(const float* __restrict__ part0, const float* __restrict__ part1, int NS,
              const float* __restrict__ w, const float* __restrict__ bias,
              float* __restrict__ out, float hw0, float hw1) {
    __shared__ float feat[512];
    int tid = threadIdx.x;
    for (int t = tid; t < 512; t += BLK) {
        int b = t >> 8, c = t & 255;
        float s = 0.f;
        if (c < 128) {
            for (int ns = 0; ns < NS; ns++) s += part0[((long)b * NS + ns) * 128 + c];
            s /= hw0;
        } else {
            int cc = c - 128;
            for (int ns = 0; ns < NS; ns++) s += part1[((long)b * NS + ns) * 128 + cc];
            s /= hw1;
        }
        feat[t] = s;
    }
    __syncthreads();
    if (tid < 4) {
        int b = tid >> 1, jj = tid & 1;
        float s = bias[jj];
        for (int c = 0; c < 256; c++) s += feat[b * 256 + c] * w[jj * 256 + c];
        out[b * 2 + jj] = s;
    }
}

static inline long cdiv(long a, long b) { return (a + b - 1) / b; }

extern "C" void kernel_launch(void* const* d_in, const int* in_sizes, int n_in,
                              void* d_out, int out_size, void* d_ws, size_t ws_size,
                              hipStream_t stream) {
    const float* x     = (const float*)d_in[0];
    const float* f0w1  = (const float*)d_in[1];
    const float* f0b1  = (const float*)d_in[2];
    const float* f0w2  = (const float*)d_in[3];
    const float* f0b2  = (const float*)d_in[4];
    const float* f0w3  = (const float*)d_in[5];
    const float* f0b3  = (const float*)d_in[6];
    const float* f0w4  = (const float*)d_in[7];
    const float* f0b4  = (const float*)d_in[8];
    const float* f1w1  = (const float*)d_in[9];
    const float* f1b1  = (const float*)d_in[10];
    const float* f1w2  = (const float*)d_in[11];
    const float* f1b2  = (const float*)d_in[12];
    const float* f1w3  = (const float*)d_in[13];
    const float* f1b3  = (const float*)d_in[14];
    const float* f1w4  = (const float*)d_in[15];
    const float* f1b4  = (const float*)d_in[16];
    const float* qw    = (const float*)d_in[17];
    const float* qb    = (const float*)d_in[18];
    const float* kw    = (const float*)d_in[19];
    const float* kb    = (const float*)d_in[20];
    const float* vw    = (const float*)d_in[21];
    const float* vb    = (const float*)d_in[22];
    const float* gamma = (const float*)d_in[23];
    const float* clsw  = (const float*)d_in[24];
    const float* clsb  = (const float*)d_in[25];
    float* ws = (float*)d_ws;
    float* outp = (float*)d_out;

    const int B = 2;
    size_t off = 0;
    auto alloc = [&](size_t nfl) { size_t o = off; off += (nfl + 63) & ~(size_t)63; return o; };
    size_t o_pool = alloc((size_t)B * 32769 * 65);
    size_t o_A0h  = alloc((size_t)B * 10923 * 22 * 32);
    size_t o_A0l  = alloc((size_t)B * 10923 * 22 * 32);
    size_t o_A1h  = alloc((size_t)B * 5462 * 11 * 32);
    size_t o_A1l  = alloc((size_t)B * 5462 * 11 * 32);
    size_t o_B0h  = alloc((size_t)B * 2731 * 6 * 64);
    size_t o_B0l  = alloc((size_t)B * 2731 * 6 * 64);
    size_t o_c0   = alloc((size_t)B * 1366 * 3 * 128);
    size_t o_c1   = alloc((size_t)B * 683 * 2 * 128);
    size_t o_w1mh = alloc((size_t)64 * 160 / 2);
    size_t o_w1ml = alloc((size_t)64 * 160 / 2);
    size_t o_w1nh = alloc((size_t)64 * 160 / 2);
    size_t o_w1nl = alloc((size_t)64 * 160 / 2);
    size_t o_w2h0 = alloc((size_t)128 * 4096 / 2);
    size_t o_w2l0 = alloc((size_t)128 * 4096 / 2);
    size_t o_w2h1 = alloc((size_t)128 * 4096 / 2);
    size_t o_w2l1 = alloc((size_t)128 * 4096 / 2);
    size_t o_w3h0 = alloc((size_t)256 * 3200 / 2);
    size_t o_w3l0 = alloc((size_t)256 * 3200 / 2);
    size_t o_w3h1 = alloc((size_t)256 * 3200 / 2);
    size_t o_w3l1 = alloc((size_t)256 * 3200 / 2);
    size_t o_w4h0 = alloc((size_t)128 * 2304 / 2);
    size_t o_w4l0 = alloc((size_t)128 * 2304 / 2);
    size_t o_w4h1 = alloc((size_t)128 * 2304 / 2);
    size_t o_w4l1 = alloc((size_t)128 * 2304 / 2);
    size_t o_wvh  = alloc((size_t)128 * 128 / 2);
    size_t o_wvl  = alloc((size_t)128 * 128 / 2);
    size_t o_part = alloc((size_t)2 * (32772 + 8196) * 128);
    size_t need_main = off;
    size_t o_B1h = o_pool;
    size_t o_B1l = o_pool + (size_t)B * 1366 * 3 * 64;
    size_t sub = o_A0h;
    auto salloc = [&](size_t nfl) { size_t o = sub; sub += (nfl + 63) & ~(size_t)63; return o; };
    size_t o_C0h = salloc((size_t)B * 1366 * 3 * 128);
    size_t o_C0l = salloc((size_t)B * 1366 * 3 * 128);
    size_t o_C1h = salloc((size_t)B * 683 * 2 * 128);
    size_t o_C1l = salloc((size_t)B * 683 * 2 * 128);
    size_t o_c0h = salloc((size_t)B * 1366 * 3 * 64);
    size_t o_c0l = salloc((size_t)B * 1366 * 3 * 64);
    size_t o_c1h = salloc((size_t)B * 683 * 2 * 64);
    size_t o_c1l = salloc((size_t)B * 683 * 2 * 64);
    size_t o_q0  = salloc((size_t)B * 1366 * 3 * 16);
    size_t o_k0  = salloc((size_t)B * 1366 * 3 * 16);
    size_t o_v0  = salloc((size_t)B * 1366 * 3 * 128);
    size_t o_a0  = salloc((size_t)B * 1366 * 3 * 128);
    size_t o_q1  = salloc((size_t)B * 683 * 2 * 16);
    size_t o_k1  = salloc((size_t)B * 683 * 2 * 16);
    size_t o_v1  = salloc((size_t)B * 683 * 2 * 128);
    size_t o_a1  = salloc((size_t)B * 683 * 2 * 128);
    size_t o_p0  = salloc((size_t)B * 8 * 128);
    size_t o_p1  = salloc((size_t)B * 8 * 128);
    if (ws_size < need_main * sizeof(float)) {
        hipMemsetAsync(d_out, 0, (size_t)out_size * sizeof(float), stream);
        return;
    }
    auto U16 = [&](size_t o) { return (u16*)(ws + o); };

    {   // pooled branch input
        long tot = (long)B * 32769 * 65;
        avgpool_synth_k<<<dim3(cdiv(tot, BLK)), BLK, 0, stream>>>(x, ws + o_pool, B);
    }
    {   // all 9 weight reorders in ONE launch
        RAll ra;
        auto mkR = [&](int i, const float* src, size_t dh, size_t dl,
                       int Cout, int Cin, int Kk, int type, long nel) {
            ra.jobs[i] = { src, U16(dh), U16(dl), Cout, Cin, Kk, type, nel };
        };
        mkR(0, f0w1, o_w1mh, o_w1ml, 64, 1, 12, 0, 64 * 160);
        mkR(1, f1w1, o_w1nh, o_w1nl, 64, 1, 12, 0, 64 * 160);
        mkR(2, f0w2, o_w2h0, o_w2l0, 128, 64, 8, 1, (long)128 * 64 * 64);
        mkR(3, f1w2, o_w2h1, o_w2l1, 128, 64, 8, 1, (long)128 * 64 * 64);
        mkR(4, f0w3, o_w3h0, o_w3l0, 256, 128, 5, 1, (long)256 * 128 * 25);
        mkR(5, f1w3, o_w3h1, o_w3l1, 256, 128, 5, 1, (long)256 * 128 * 25);
        mkR(6, f0w4, o_w4h0, o_w4l0, 128, 256, 3, 1, (long)128 * 256 * 9);
        mkR(7, f1w4, o_w4h1, o_w4l1, 128, 256, 3, 1, (long)128 * 256 * 9);
        mkR(8, vw,   o_wvh,  o_wvl,  128, 128, 1, 1, (long)128 * 128);
        int acc2 = 0;
        for (int i = 0; i < 9; i++) {
            ra.bstart[i] = acc2;
            acc2 += (int)cdiv(ra.jobs[i].nel, BLK);
        }
        ra.bstart[9] = acc2;
        reorder_all_k<<<dim3(acc2), BLK, 0, stream>>>(ra);
    }
    {   // f1 conv1: MFMA patch kernel over pool plane -> A1 hi/lo
        int nbx = (int)cdiv(60082L, 128);   // 470
        conv1p_mfma_k<<<dim3(nbx, B), 256, 0, stream>>>(
            ws + o_pool, U16(o_w1nh), U16(o_w1nl), f1b1, U16(o_A1h), U16(o_A1l));
    }
    {   // f0 conv1: MFMA implicit GEMM over virtual c_in -> A0 hi/lo
        int nbx = (int)cdiv(240306L, 128);   // 1878
        conv1_mfma_k<<<dim3(nbx, B), 256, 0, stream>>>(
            x, U16(o_w1mh), U16(o_w1ml), f0b1, U16(o_A0h), U16(o_A0l));
    }

    float* partp = ws + o_part;
    auto mkM = [&](size_t ah, size_t al, size_t wh, size_t wl, const float* bias, float* out,
                   int Hin, int Win, int Cin, int cshift, int Cout,
                   int K, int S, int P, int Hout, int Wout, int relu) {
        MJob g;
        g.Ah = U16(ah); g.Al = U16(al); g.Wh = U16(wh); g.Wl = U16(wl);
        g.bias = bias; g.out = out; g.part = nullptr;
        g.Hin = Hin; g.Win = Win; g.Cin = Cin; g.cshift = cshift; g.Cout = Cout;
        g.K = K; g.S = S; g.P = P; g.Hout = Hout; g.Wout = Wout; g.relu = relu; g.nks = 1;
        g.total = (long)B * Hout * Wout;
        g.nbx = (int)((g.total + 127) / 128);
        g.Ktot = K * K * Cin;
        return g;
    };
    auto launchM = [&](MJob a, MJob b, int nks) {
        a.nks = nks; b.nks = nks;
        a.part = partp;
        b.part = partp + (size_t)nks * a.total * a.Cout;
        int na = a.nbx * (a.Cout >> 7) * nks;
        int nb = b.nbx * (b.Cout >> 7) * nks;
        mgemm2_k<<<dim3(na + nb), 256, 0, stream>>>(a, b, na);
    };

    // conv2: A0/A1 -> B0/B1 (bf16 hi/lo), split-K 2
    {
        MJob a = mkM(o_A0h, o_A0l, o_w2h0, o_w2l0, f0b2, nullptr, 10923, 22, 64, 6, 128, 8, 4, 4, 2731, 6, 1);
        MJob b = mkM(o_A1h, o_A1l, o_w2h1, o_w2l1, f1b2, nullptr, 5462, 11, 64, 6, 128, 8, 4, 4, 1366, 3, 1);
        launchM(a, b, 2);
        CJob ca = {partp, f0b2, nullptr, U16(o_B0h), U16(o_B0l), a.total, 128, 2, 1};
        CJob cb = {partp + (size_t)2 * a.total * 128, f1b2, nullptr, U16(o_B1h), U16(o_B1l), b.total, 128, 2, 1};
        long n4 = (a.total * 128 + b.total * 128) / 4;
        combine2m_k<<<dim3(cdiv(n4, BLK)), BLK, 0, stream>>>(ca, cb);
    }
    // conv3: B0/B1 -> C0/C1 (bf16 hi/lo), split-K 3
    {
        MJob a = mkM(o_B0h, o_B0l, o_w3h0, o_w3l0, f0b3, nullptr, 2731, 6, 128, 7, 256, 5, 2, 2, 1366, 3, 1);
        MJob b = mkM(o_B1h, o_B1l, o_w3h1, o_w3l1, f1b3, nullptr, 1366, 3, 128, 7, 256, 5, 2, 2, 683, 2, 1);
        launchM(a, b, 3);
        CJob ca = {partp, f0b3, nullptr, U16(o_C0h), U16(o_C0l), a.total, 256, 3, 1};
        CJob cb = {partp + (size_t)3 * a.total * 256, f1b3, nullptr, U16(o_C1h), U16(o_C1l), b.total, 256, 3, 1};
        long n4 = (a.total * 256 + b.total * 256) / 4;
        combine2m_k<<<dim3(cdiv(n4, BLK)), BLK, 0, stream>>>(ca, cb);
    }
    // conv4: C0/C1 -> c0/c1 (fp32 + bf16 hi/lo), split-K 6
    {
        MJob a = mkM(o_C0h, o_C0l, o_w4h0, o_w4l0, f0b4, nullptr, 1366, 3, 256, 8, 128, 3, 1, 1, 1366, 3, 1);
        MJob b = mkM(o_C1h, o_C1l, o_w4h1, o_w4l1, f1b4, nullptr, 683, 2, 256, 8, 128, 3, 1, 1, 683, 2, 1);
        launchM(a, b, 6);
        CJob ca = {partp, f0b4, ws + o_c0, U16(o_c0h), U16(o_c0l), a.total, 128, 6, 1};
        CJob cb = {partp + (size_t)6 * a.total * 128, f1b4, ws + o_c1, U16(o_c1h), U16(o_c1l), b.total, 128, 6, 1};
        long n4 = (a.total * 128 + b.total * 128) / 4;
        combine2m_k<<<dim3(cdiv(n4, BLK)), BLK, 0, stream>>>(ca, cb);
    }
    // q,k projections (fp32 from c0/c1)
    {
        long tot0 = (long)B * 1366 * 3;
        qk2_k<<<dim3(cdiv(tot0, 64), 2), 256, 0, stream>>>(
            ws + o_c0, qw, qb, kw, kb, ws + o_q0, ws + o_k0, tot0);
        long tot1 = (long)B * 683 * 2;
        qk2_k<<<dim3(cdiv(tot1, 64), 2), 256, 0, stream>>>(
            ws + o_c1, qw, qb, kw, kb, ws + o_q1, ws + o_k1, tot1);
    }
    // v projection (MFMA, nks=1, direct fp32 out, no relu)
    {
        MJob a = mkM(o_c0h, o_c0l, o_wvh, o_wvl, vb, ws + o_v0, 1366, 3, 128, 7, 128, 1, 1, 0, 1366, 3, 0);
        MJob b = mkM(o_c1h, o_c1l, o_wvh, o_wvl, vb, ws + o_v1, 683, 2, 128, 7, 128, 1, 1, 0, 683, 2, 0);
        launchM(a, b, 1);
    }
    // CCA: split-KV flash partials (both branches, one launch) + combine
    {
        const int nrt0 = 86, nrt1 = 43;
        const int ns0 = 6, ns1 = 3;
        const long rows0 = (long)B * 1366 * 3;   // 8196
        const long rows1 = (long)B * 683 * 2;    // 2732
        size_t pp = o_part;
        auto palloc = [&](size_t nfl) { size_t o = pp; pp += (nfl + 63) & ~(size_t)63; return o; };
        size_t o_pa0 = palloc((size_t)rows0 * ns0 * 128);
        size_t o_pm0 = palloc((size_t)rows0 * ns0);
        size_t o_pl0 = palloc((size_t)rows0 * ns0);
        size_t o_pa1 = palloc((size_t)rows1 * ns1 * 128);
        size_t o_pm1 = palloc((size_t)rows1 * ns1);
        size_t o_pl1 = palloc((size_t)rows1 * ns1);
        AJob a0 = { ws + o_q0, ws + o_k0, ws + o_v0,
                    ws + o_pa0, ws + o_pm0, ws + o_pl0, B, 1366, 3, nrt0, ns0, 22 };
        AJob a1 = { ws + o_q1, ws + o_k1, ws + o_v1,
                    ws + o_pa1, ws + o_pm1, ws + o_pl1, B, 683, 2, nrt1, ns1, 11 };
        int n0 = B * 3 * nrt0 * ns0;   // 3096
        int n1 = B * 2 * nrt1 * ns1;   // 516
        cca_part_k<<<dim3(n0 + n1), 256, 0, stream>>>(a0, a1, n0);
        CCJob c0 = { ws + o_c0, ws + o_pa0, ws + o_pm0, ws + o_pl0, ws + o_a0, rows0, ns0 };
        CCJob c1 = { ws + o_c1, ws + o_pa1, ws + o_pm1, ws + o_pl1, ws + o_a1, rows1, ns1 };
        long tot = (rows0 + rows1) * 32;
        cca_comb_k<<<dim3(cdiv(tot, BLK)), BLK, 0, stream>>>(c0, c1, gamma);
    }
    // means + classifier
    mean_part_k<<<dim3(B * 8), BLK, 0, stream>>>(ws + o_a0, ws + o_p0, 1366 * 3, 8);
    mean_part_k<<<dim3(B * 8), BLK, 0, stream>>>(ws + o_a1, ws + o_p1, 683 * 2, 8);
    final2_k<<<dim3(1), BLK, 0, stream>>>(ws + o_p0, ws + o_p1, 8, clsw, clsb, outp,
                                          (float)(1366 * 3), (float)(683 * 2));
}